// Round 7
// baseline (1066.528 us; speedup 1.0000x reference)
//
#include <hip/hip_runtime.h>
#include <hip/hip_bf16.h>
#include <math.h>

#define N_ 40000
#define E_ 640000
#define CB_ 400   // k_coarse partial blocks
#define CR_ 100   // rows per block (CB_*CR_ == N_)
#define SB_ 256
#define SNB_ 157  // ceil(N_/SB_)

typedef short bf16x8 __attribute__((ext_vector_type(8)));
typedef float floatx4 __attribute__((ext_vector_type(4)));

__device__ __forceinline__ short f2bf(float f) {
    __hip_bfloat16 h = __float2bfloat16(f);
    return *reinterpret_cast<short*>(&h);
}
__device__ __forceinline__ float bf2f(short u) {
    unsigned int x = ((unsigned int)(unsigned short)u) << 16;
    return __int_as_float(x);
}
__device__ __forceinline__ float rdlane(float v, int l) {
    return __int_as_float(__builtin_amdgcn_readlane(__float_as_int(v), l));
}
// unpack 2 bf16 packed in a uint
__device__ __forceinline__ float bflo(unsigned int u) { return __int_as_float(u << 16); }
__device__ __forceinline__ float bfhi(unsigned int u) { return __int_as_float(u & 0xffff0000u); }

// ---------------- CSR build ----------------
__global__ void k_count(const int* __restrict__ dst, int* __restrict__ counts) {
    for (int e = blockIdx.x * blockDim.x + threadIdx.x; e < E_; e += gridDim.x * blockDim.x)
        atomicAdd(&counts[dst[e]], 1);
}

// ---- 3-phase parallel scan ----
__global__ __launch_bounds__(256) void k_scanA(const int* __restrict__ counts,
                                               int* __restrict__ excl,
                                               int* __restrict__ bsum) {
    int t = threadIdx.x;
    int i = blockIdx.x * SB_ + t;
    int v = (i < N_) ? counts[i] : 0;
    int lane = t & 63, wv = t >> 6;
    int x = v;
#pragma unroll
    for (int off = 1; off < 64; off <<= 1) {
        int y = __shfl_up(x, off);
        if (lane >= off) x += y;
    }
    __shared__ int wsum[4];
    __shared__ int woff[4];
    if (lane == 63) wsum[wv] = x;
    __syncthreads();
    if (t == 0) {
        int a = 0;
#pragma unroll
        for (int j = 0; j < 4; j++) { int tv = wsum[j]; woff[j] = a; a += tv; }
        bsum[blockIdx.x] = a;
    }
    __syncthreads();
    if (i < N_) excl[i] = x - v + woff[wv];
}

__global__ __launch_bounds__(256) void k_scanB(int* __restrict__ bsum) {
    int t = threadIdx.x;
    int v = (t < SNB_) ? bsum[t] : 0;
    int lane = t & 63, wv = t >> 6;
    int x = v;
#pragma unroll
    for (int off = 1; off < 64; off <<= 1) {
        int y = __shfl_up(x, off);
        if (lane >= off) x += y;
    }
    __shared__ int wsum[4];
    __shared__ int woff[4];
    if (lane == 63) wsum[wv] = x;
    __syncthreads();
    if (t == 0) {
        int a = 0;
#pragma unroll
        for (int j = 0; j < 4; j++) { int tv = wsum[j]; woff[j] = a; a += tv; }
    }
    __syncthreads();
    if (t < SNB_) bsum[t] = x - v + woff[wv];
}

__global__ __launch_bounds__(256) void k_scanC(const int* __restrict__ excl,
                                               const int* __restrict__ bsum,
                                               int* __restrict__ rowptr,
                                               int* __restrict__ cursor) {
    int i = blockIdx.x * 256 + threadIdx.x;
    if (i < N_) {
        int r = excl[i] + bsum[i / SB_];
        rowptr[i] = r;
        cursor[i] = r;
    }
    if (i == N_) rowptr[N_] = E_;
}

__global__ void k_fill(const int* __restrict__ src, const int* __restrict__ dst,
                       int* __restrict__ cursor, int* __restrict__ srcv,
                       unsigned short* __restrict__ dstv, int* __restrict__ eidv) {
    for (int e = blockIdx.x * blockDim.x + threadIdx.x; e < E_; e += gridDim.x * blockDim.x) {
        int d = dst[e];
        int pos = atomicAdd(&cursor[d], 1);
        srcv[pos] = src[e];
        dstv[pos] = (unsigned short)d;
        eidv[pos] = e;
    }
}

// ---------------- prep: 6x fp32 [k=128][n=128] -> bf16 [n][k] ----------------
__global__ __launch_bounds__(256) void k_prep_all(const float* __restrict__ Wg,
                                                  const float* __restrict__ W3,
                                                  const float* __restrict__ Wm1,
                                                  short* __restrict__ WbT6) {
    int i = blockIdx.x * 256 + threadIdx.x;   // 6*16384 total
    if (i >= 6 * 16384) return;
    int m = i >> 14;
    int r = i & 16383;
    int n = r >> 7, k = r & 127;
    const float* srcp;
    switch (m) {
        case 0: srcp = Wg; break;
        case 1: srcp = Wg + 16384; break;
        case 2: srcp = Wg + 32768; break;
        case 3: srcp = W3; break;
        case 4: srcp = Wm1; break;
        default: srcp = Wm1 + 16384; break;
    }
    WbT6[m * 16384 + n * 128 + k] = f2bf(srcp[k * 128 + n]);
}

// ---------------- prep: hi/lo bf16 splits of W_emb [128,128] and Wa [128,100] ----------------
// outputs transposed [n][k]; Wa zero-padded to n=128
__global__ __launch_bounds__(256) void k_prep_hilo(const float* __restrict__ W_emb,
                                                   const float* __restrict__ Wa,
                                                   short* __restrict__ WembT_hi,
                                                   short* __restrict__ WembT_lo,
                                                   short* __restrict__ WaT_hi,
                                                   short* __restrict__ WaT_lo) {
    int i = blockIdx.x * 256 + threadIdx.x;   // 2*16384 total
    if (i >= 2 * 16384) return;
    int m = i >> 14;
    int r = i & 16383;
    int n = r >> 7, k = r & 127;
    if (m == 0) {
        float w = W_emb[k * 128 + n];
        short h = f2bf(w);
        WembT_hi[n * 128 + k] = h;
        WembT_lo[n * 128 + k] = f2bf(w - bf2f(h));
    } else {
        float w = (n < 100) ? Wa[k * 100 + n] : 0.f;
        short h = f2bf(w);
        WaT_hi[n * 128 + k] = h;
        WaT_lo[n * 128 + k] = f2bf(w - bf2f(h));
    }
}

// ---------------- fp32-accurate MFMA GEMM via 3-term hi/lo split ----------------
// C[64rows x ncols] = A(fp32) @ B(fp32 decomposed as bf16 hi+lo), fp32 out.
// C = Ah@Bh + Al@Bh + Ah@Bl  (dropped Al@Bl ~ 2^-16 relative).
// A hi/lo staged in LDS; B_hi in LDS; B_lo fragments read from global (32KB, L2-resident).
__global__ __launch_bounds__(256) void k_mfma_hilo(const float* __restrict__ A,
                                                   const short* __restrict__ BT_hi,
                                                   const short* __restrict__ BT_lo,
                                                   const float* __restrict__ bias,
                                                   float* __restrict__ C, int ncols) {
    __shared__ short sAh[64 * 136];
    __shared__ short sAl[64 * 136];
    __shared__ short sBh[128 * 136];
    int t = threadIdx.x;
    int r0 = blockIdx.x * 64;
    // stage B_hi: each thread copies 64 bf16
    {
        int n = t >> 1;
        int k0 = (t & 1) * 64;
#pragma unroll
        for (int j = 0; j < 8; j++) {
            bf16x8 v = *(const bf16x8*)(BT_hi + n * 128 + k0 + 8 * j);
            *(bf16x8*)(sBh + n * 136 + k0 + 8 * j) = v;
        }
    }
    // stage A hi/lo: each thread converts 32 floats
    {
        int r = t >> 2;
        int k0 = (t & 3) * 32;
        const float* ar = A + (size_t)(r0 + r) * 128 + k0;
#pragma unroll
        for (int j = 0; j < 4; j++) {
            float4 f0 = *(const float4*)(ar + 8 * j);
            float4 f1 = *(const float4*)(ar + 8 * j + 4);
            float x[8] = {f0.x, f0.y, f0.z, f0.w, f1.x, f1.y, f1.z, f1.w};
            bf16x8 vh, vl;
#pragma unroll
            for (int q = 0; q < 8; q++) {
                short hh = f2bf(x[q]);
                vh[q] = hh;
                vl[q] = f2bf(x[q] - bf2f(hh));
            }
            *(bf16x8*)(sAh + r * 136 + k0 + 8 * j) = vh;
            *(bf16x8*)(sAl + r * 136 + k0 + 8 * j) = vl;
        }
    }
    __syncthreads();
    int lane = t & 63, wv = t >> 6;
    int lm = lane & 15, quad = lane >> 4;
    int m0 = wv * 16;
    bf16x8 aH[4], aL[4];
#pragma unroll
    for (int kt = 0; kt < 4; kt++) {
        aH[kt] = *(const bf16x8*)(sAh + (m0 + lm) * 136 + kt * 32 + quad * 8);
        aL[kt] = *(const bf16x8*)(sAl + (m0 + lm) * 136 + kt * 32 + quad * 8);
    }
#pragma unroll
    for (int nt = 0; nt < 8; nt++) {
        const short* blp = BT_lo + (nt * 16 + lm) * 128 + quad * 8;
        floatx4 acc = (floatx4){0.f, 0.f, 0.f, 0.f};
#pragma unroll
        for (int kt = 0; kt < 4; kt++) {
            bf16x8 bH = *(const bf16x8*)(sBh + (nt * 16 + lm) * 136 + kt * 32 + quad * 8);
            bf16x8 bL = *(const bf16x8*)(blp + kt * 32);
            acc = __builtin_amdgcn_mfma_f32_16x16x32_bf16(aH[kt], bH, acc, 0, 0, 0);
            acc = __builtin_amdgcn_mfma_f32_16x16x32_bf16(aL[kt], bH, acc, 0, 0, 0);
            acc = __builtin_amdgcn_mfma_f32_16x16x32_bf16(aH[kt], bL, acc, 0, 0, 0);
        }
        int col = nt * 16 + lm;
        if (col < ncols) {
            float bv = bias ? bias[col] : 0.f;
#pragma unroll
            for (int r = 0; r < 4; r++) {
                int row = r0 + m0 + quad * 4 + r;
                C[(size_t)row * ncols + col] = acc[r] + bv;
            }
        }
    }
}

// ---------------- MFMA GEMM: [N,128](fp32) @ WbT(bf16 [n][k]) -> bf16 out ----------------
// 64 rows/block, full N=128. A converted fp32->bf16 into LDS (+8 pad = 2-way bank, free).
__global__ __launch_bounds__(256) void k_gemm_mfma(const float* __restrict__ A,
                                                   const short* __restrict__ WbT,
                                                   const float* __restrict__ bias,
                                                   short* __restrict__ C) {
    __shared__ short sA[64 * 136];
    __shared__ short sB[128 * 136];
    int t = threadIdx.x;
    int r0 = blockIdx.x * 64;
    // stage B: each thread copies 64 bf16
    {
        int n = t >> 1;
        int k0 = (t & 1) * 64;
#pragma unroll
        for (int j = 0; j < 8; j++) {
            bf16x8 v = *(const bf16x8*)(WbT + n * 128 + k0 + 8 * j);
            *(bf16x8*)(sB + n * 136 + k0 + 8 * j) = v;
        }
    }
    // stage A: each thread converts 32 floats
    {
        int r = t >> 2;
        int k0 = (t & 3) * 32;
        const float* ar = A + (size_t)(r0 + r) * 128 + k0;
#pragma unroll
        for (int j = 0; j < 4; j++) {
            float4 f0 = *(const float4*)(ar + 8 * j);
            float4 f1 = *(const float4*)(ar + 8 * j + 4);
            bf16x8 v;
            v[0] = f2bf(f0.x); v[1] = f2bf(f0.y); v[2] = f2bf(f0.z); v[3] = f2bf(f0.w);
            v[4] = f2bf(f1.x); v[5] = f2bf(f1.y); v[6] = f2bf(f1.z); v[7] = f2bf(f1.w);
            *(bf16x8*)(sA + r * 136 + k0 + 8 * j) = v;
        }
    }
    __syncthreads();
    int lane = t & 63, wv = t >> 6;
    int lm = lane & 15, quad = lane >> 4;
    int m0 = wv * 16;
    bf16x8 aF[4];
#pragma unroll
    for (int kt = 0; kt < 4; kt++)
        aF[kt] = *(const bf16x8*)(sA + (m0 + lm) * 136 + kt * 32 + quad * 8);
#pragma unroll
    for (int nt = 0; nt < 8; nt++) {
        floatx4 acc = (floatx4){0.f, 0.f, 0.f, 0.f};
#pragma unroll
        for (int kt = 0; kt < 4; kt++) {
            bf16x8 bF = *(const bf16x8*)(sB + (nt * 16 + lm) * 136 + kt * 32 + quad * 8);
            acc = __builtin_amdgcn_mfma_f32_16x16x32_bf16(aF[kt], bF, acc, 0, 0, 0);
        }
        int col = nt * 16 + lm;
        float bv = bias ? bias[col] : 0.f;
#pragma unroll
        for (int r = 0; r < 4; r++) {
            int row = r0 + m0 + quad * 4 + r;
            C[(size_t)row * 128 + col] = f2bf(acc[r] + bv);
        }
    }
}

// ---------------- softmax over 100 logits, wave per node, barrier-free ----------------
__global__ __launch_bounds__(256) void k_smax100(const float* __restrict__ logits,
                                                 float* __restrict__ s) {
    int lane = threadIdx.x & 63;
    int n = blockIdx.x * 4 + (threadIdx.x >> 6);
    if (n >= N_) return;
    bool act = lane < 50;
    float2 v = make_float2(-INFINITY, -INFINITY);
    if (act) v = *(const float2*)(logits + (size_t)n * 100 + 2 * lane);
    float mx = fmaxf(v.x, v.y);
#pragma unroll
    for (int off = 1; off < 64; off <<= 1) mx = fmaxf(mx, __shfl_xor(mx, off));
    float e0 = act ? __expf(v.x - mx) : 0.f;
    float e1 = act ? __expf(v.y - mx) : 0.f;
    float sm = e0 + e1;
#pragma unroll
    for (int off = 1; off < 64; off <<= 1) sm += __shfl_xor(sm, off);
    float inv = 1.f / sm;
    if (act) *(float2*)(s + (size_t)n * 100 + 2 * lane) = make_float2(e0 * inv, e1 * inv);
}

// ---------------- per-node attention logits el/er (bf16 feat) ----------------
template <int H>
__global__ __launch_bounds__(256) void k_elr(const short* __restrict__ feat,
                                             const float* __restrict__ al,
                                             const float* __restrict__ ar,
                                             float* __restrict__ el, float* __restrict__ er) {
    int lane = threadIdx.x & 63;
    int n = blockIdx.x * 4 + (threadIdx.x >> 6);
    if (n >= N_) return;
    unsigned int u = *(const unsigned int*)(feat + (size_t)n * 128 + 2 * lane);
    float fx = bflo(u), fy = bfhi(u);
    float2 a = *(const float2*)(al + 2 * lane);
    float2 b = *(const float2*)(ar + 2 * lane);
    float pl = fx * a.x + fy * a.y;
    float pr = fx * b.x + fy * b.y;
    constexpr int G = 64 / H;
#pragma unroll
    for (int off = 1; off < G; off <<= 1) {
        pl += __shfl_xor(pl, off);
        pr += __shfl_xor(pr, off);
    }
    if ((lane & (G - 1)) == 0) {
        int hh = lane / G;
        el[(size_t)n * H + hh] = pl;
        er[(size_t)n * H + hh] = pr;
    }
}

// ---------------- GAT edge-softmax + aggregate (wave per dst node, bf16 feat) ----------------
// v5: (a) pass 1 now 2-chunk interleaved like pass 2 — both srcv->el gather chains
// issued before either online update, doubling loads-in-flight in the latency-bound
// stats pass; (b) BN column stats (sum/sumsq of xout) fused into the epilogue:
// per-thread accumulators over owned cols f0,f0+1, block LDS reduce, 4 atomicAdds
// per lane-col — replaces the separate k_bn_stats pass over 20MB.
template <int H>
__global__ __launch_bounds__(256) void k_gat_agg(const short* __restrict__ feat,
                                                 const float* __restrict__ el,
                                                 const float* __restrict__ er,
                                                 const int* __restrict__ rowptr,
                                                 const int* __restrict__ srcv,
                                                 const float* __restrict__ bias,
                                                 float* __restrict__ xout,
                                                 float* __restrict__ csum,
                                                 float* __restrict__ csq) {
    int t = threadIdx.x;
    int lane = t & 63;
    int gw = (blockIdx.x * blockDim.x + t) >> 6;
    int nw = (gridDim.x * blockDim.x) >> 6;
    constexpr int LH = (H == 8) ? 3 : 0;
    constexpr int STEP = 64 >> LH;
    int h = lane & (H - 1);
    int f0 = 2 * lane;
    int hf = (H == 8) ? (lane >> 3) : 0;   // head owning this lane's feature slice

    float stx = 0.f, sty = 0.f, qtx = 0.f, qty = 0.f;  // fused BN stats

    for (int n = gw; n < N_; n += nw) {
        int beg = rowptr[n], end = rowptr[n + 1];
        if (beg == end) {
            float2 b2 = *(const float2*)(bias + f0);
            *(float2*)(xout + (size_t)n * 128 + f0) = b2;
            stx += b2.x; sty += b2.y;
            qtx += b2.x * b2.x; qty += b2.y * b2.y;
            continue;
        }
        float ern = er[(size_t)n * H + h];
        // ---- pass 1: online softmax stats, 2-chunk interleaved ----
        float m = -INFINITY, ss = 0.f;
        int e = beg + (lane >> LH);
        for (; e + STEP < end; e += 2 * STEP) {
            int sA = srcv[e];
            int sB = srcv[e + STEP];
            float xA = el[(size_t)sA * H + h] + ern;
            float xB = el[(size_t)sB * H + h] + ern;
            float lrA = xA > 0.f ? xA : 0.2f * xA;
            float lrB = xB > 0.f ? xB : 0.2f * xB;
            if (lrA > m) { ss = ss * __expf(m - lrA) + 1.f; m = lrA; }
            else ss += __expf(lrA - m);
            if (lrB > m) { ss = ss * __expf(m - lrB) + 1.f; m = lrB; }
            else ss += __expf(lrB - m);
        }
        if (e < end) {
            int sA = srcv[e];
            float xA = el[(size_t)sA * H + h] + ern;
            float lrA = xA > 0.f ? xA : 0.2f * xA;
            if (lrA > m) { ss = ss * __expf(m - lrA) + 1.f; m = lrA; }
            else ss += __expf(lrA - m);
        }
#pragma unroll
        for (int off = H; off < 64; off <<= 1) {
            float om = __shfl_xor(m, off);
            float os = __shfl_xor(ss, off);
            float nm = fmaxf(m, om);
            float p1 = (m == -INFINITY) ? 0.f : ss * __expf(m - nm);
            float p2 = (om == -INFINITY) ? 0.f : os * __expf(om - nm);
            m = nm; ss = p1 + p2;
        }
        // after butterfly each lane holds (m, ss) for its own head h = lane&(H-1)
        float inv_d = 1.f / ss;
        // ---- pass 2: 2x interleaved chunked aggregation ----
        int endm1 = end - 1;
        float accx = 0.f, accy = 0.f;
        for (int e0 = beg; e0 < end; e0 += 16) {
            int le = lane >> 3;
            int eLA = e0 + le, eLB = e0 + 8 + le;
            int eCA = eLA <= endm1 ? eLA : endm1;
            int eCB = eLB <= endm1 ? eLB : endm1;
            int sLA = srcv[eCA];
            int sLB = srcv[eCB];
            float xA = el[(size_t)sLA * H + h] + ern;
            float xB = el[(size_t)sLB * H + h] + ern;
            float lrA = xA > 0.f ? xA : 0.2f * xA;
            float lrB = xB > 0.f ? xB : 0.2f * xB;
            float wA = __expf(lrA - m) * inv_d;
            float wB = __expf(lrB - m) * inv_d;
            if (eLA > endm1) wA = 0.f;
            if (eLB > endm1) wB = 0.f;
            bool haveB = (e0 + 8) < end;    // wave-uniform
            unsigned int uuA[8], uuB[8];
#pragma unroll
            for (int j = 0; j < 8; j++) {
                int sj = __builtin_amdgcn_readlane(sLA, j * 8);
                uuA[j] = *(const unsigned int*)(feat + (size_t)sj * 128 + f0);
            }
            if (haveB) {
#pragma unroll
                for (int j = 0; j < 8; j++) {
                    int sj = __builtin_amdgcn_readlane(sLB, j * 8);
                    uuB[j] = *(const unsigned int*)(feat + (size_t)sj * 128 + f0);
                }
            }
#pragma unroll
            for (int j = 0; j < 8; j++) {
                float aj;
                if (H == 8) aj = __shfl(wA, j * 8 + hf);
                else        aj = rdlane(wA, j * 8);
                accx += aj * bflo(uuA[j]);
                accy += aj * bfhi(uuA[j]);
            }
            if (haveB) {
#pragma unroll
                for (int j = 0; j < 8; j++) {
                    float aj;
                    if (H == 8) aj = __shfl(wB, j * 8 + hf);
                    else        aj = rdlane(wB, j * 8);
                    accx += aj * bflo(uuB[j]);
                    accy += aj * bfhi(uuB[j]);
                }
            }
        }
        float2 b2 = *(const float2*)(bias + f0);
        float ox = accx + b2.x, oy = accy + b2.y;
        *(float2*)(xout + (size_t)n * 128 + f0) = make_float2(ox, oy);
        stx += ox; sty += oy;
        qtx += ox * ox; qty += oy * oy;
    }

    // ---- fused BN stats: block reduce (4 waves share lane->col mapping) + atomics ----
    __shared__ float red[4][256];
    red[0][t] = stx; red[1][t] = sty; red[2][t] = qtx; red[3][t] = qty;
    __syncthreads();
    if (t < 64) {
        float a0 = red[0][t] + red[0][t + 64] + red[0][t + 128] + red[0][t + 192];
        float a1 = red[1][t] + red[1][t + 64] + red[1][t + 128] + red[1][t + 192];
        float q0 = red[2][t] + red[2][t + 64] + red[2][t + 128] + red[2][t + 192];
        float q1 = red[3][t] + red[3][t + 64] + red[3][t + 128] + red[3][t + 192];
        atomicAdd(&csum[2 * t], a0);
        atomicAdd(&csum[2 * t + 1], a1);
        atomicAdd(&csq[2 * t], q0);
        atomicAdd(&csq[2 * t + 1], q1);
    }
}

// ---------------- BN apply + ELU + residual (+mask) ----------------
__global__ __launch_bounds__(256) void k_bn_apply(const float* __restrict__ x,
                                                  const float* __restrict__ hprev,
                                                  const float* __restrict__ sum,
                                                  const float* __restrict__ sumsq,
                                                  const float* __restrict__ g,
                                                  const float* __restrict__ b,
                                                  float* __restrict__ out, int do_mask) {
    int i = blockIdx.x * blockDim.x + threadIdx.x;
    if (i >= N_ * 128) return;
    int c = i & 127;
    const float invN = 1.f / (float)N_;
    float mu = sum[c] * invN;
    float var = sumsq[c] * invN - mu * mu;
    float inv = rsqrtf(var + 1e-5f);
    float y = g[c] * (x[i] - mu) * inv + b[c];
    y = y > 0.f ? y : (__expf(y) - 1.f);
    float hv = hprev[i] + y;
    if (do_mask && isinf(hv)) hv = 1e9f;
    out[i] = hv;
}

// ---------------- h_coarse partials ----------------
__global__ __launch_bounds__(512) void k_coarse_part(const float* __restrict__ s,
                                                     const float* __restrict__ hf,
                                                     float* __restrict__ part) {
    int t = threadIdx.x;
    int c = t & 127;
    int g = t >> 7;        // 0..3
    int lane = t & 63;
    float acc[25];
#pragma unroll
    for (int a = 0; a < 25; a++) acc[a] = 0.f;
    int n0 = blockIdx.x * CR_;
    for (int n = n0; n < n0 + CR_; n += 2) {
        float hv0 = hf[(size_t)n * 128 + c];
        float hv1 = hf[(size_t)(n + 1) * 128 + c];
        float sv0 = 0.f, sv1 = 0.f;
        if (lane < 25) {
            sv0 = s[(size_t)n * 100 + 25 * g + lane];
            sv1 = s[(size_t)(n + 1) * 100 + 25 * g + lane];
        }
#pragma unroll
        for (int a = 0; a < 25; ++a) {
            float a0 = rdlane(sv0, a);
            float a1 = rdlane(sv1, a);
            acc[a] += a0 * hv0 + a1 * hv1;
        }
    }
    float* dstp = part + (size_t)blockIdx.x * 12800 + (size_t)(25 * g) * 128 + c;
#pragma unroll
    for (int a = 0; a < 25; a++) dstp[a * 128] = acc[a];
}

// ---------------- reduce partials -> hc[100][128] ----------------
__global__ __launch_bounds__(256) void k_coarse_reduce(const float* __restrict__ part,
                                                       float* __restrict__ hc) {
    int i = blockIdx.x * blockDim.x + threadIdx.x;  // 12800 total
    if (i >= 12800) return;
    float s0 = 0.f, s1 = 0.f, s2 = 0.f, s3 = 0.f;
    for (int b = 0; b < CB_; b += 4) {
        s0 += part[(size_t)(b + 0) * 12800 + i];
        s1 += part[(size_t)(b + 1) * 12800 + i];
        s2 += part[(size_t)(b + 2) * 12800 + i];
        s3 += part[(size_t)(b + 3) * 12800 + i];
    }
    hc[i] = (s0 + s1) + (s2 + s3);
}

// ---------------- h = mask(0.5*h_fine + 0.5*(s@h_coarse)) ----------------
// v3: 16 nodes/block (hc reused 16x), s tile staged in LDS (6.4KB, coalesced),
// compute reads are same-address LDS broadcasts + coalesced hc loads.
__global__ __launch_bounds__(256) void k_combine(const float* __restrict__ s,
                                                 const float* __restrict__ hc,
                                                 const float* __restrict__ hfine,
                                                 float* __restrict__ hout) {
    __shared__ float ssh[16 * 100];
    int t = threadIdx.x;
    int n0 = blockIdx.x * 16;
    for (int u = t; u < 1600; u += 256) ssh[u] = s[(size_t)n0 * 100 + u];
    __syncthreads();
    int c = t & 127, g = t >> 7;
    float acc[8];
#pragma unroll
    for (int r = 0; r < 8; r++) acc[r] = 0.f;
    const float* hcp = hc + c;
    for (int a = 0; a < 100; a += 4) {
        float h0 = hcp[(a + 0) * 128];
        float h1 = hcp[(a + 1) * 128];
        float h2 = hcp[(a + 2) * 128];
        float h3 = hcp[(a + 3) * 128];
#pragma unroll
        for (int r = 0; r < 8; r++) {
            float4 sv = *(const float4*)(ssh + (g * 8 + r) * 100 + a);
            acc[r] += sv.x * h0 + sv.y * h1 + sv.z * h2 + sv.w * h3;
        }
    }
#pragma unroll
    for (int r = 0; r < 8; r++) {
        int row = n0 + g * 8 + r;
        float v = 0.5f * hfine[(size_t)row * 128 + c] + 0.5f * acc[r];
        if (isinf(v)) v = 1e9f;
        hout[(size_t)row * 128 + c] = v;
    }
}

// ---------------- prep: Wm2 [128][64] fp32 -> Wm2T bf16 [64][128] ----------------
__global__ __launch_bounds__(256) void k_prep_w(const float* __restrict__ Wm2,
                                                short* __restrict__ Wm2T) {
    int i = blockIdx.x * blockDim.x + threadIdx.x;  // 8192 total
    if (i >= 64 * 128) return;
    int n = i & 63, k = i >> 6;
    Wm2T[n * 128 + k] = f2bf(Wm2[k * 64 + n]);
}

// ---------------- edge MLP readout: dst-sorted order, barrier-free persistent MFMA ----------------
// v2 (do not register-diet: forcing 8 waves/EU -> VGPR 32 -> scratch spills ->
// 6x FETCH_SIZE and 3x dur. At VGPR=84 the 8-gather ILP covers latency).
__global__ __launch_bounds__(256) void k_edge_mlp3(const short* __restrict__ Pb,
                                                   const short* __restrict__ Qb,
                                                   const int* __restrict__ srcv,
                                                   const unsigned short* __restrict__ dstv,
                                                   const int* __restrict__ eidv,
                                                   const short* __restrict__ Wm2T,
                                                   const float* __restrict__ bm2,
                                                   const float* __restrict__ Wm3,
                                                   const float* __restrict__ bm3,
                                                   float* __restrict__ zout) {
    __shared__ short sW[64 * 128];  // 16 KiB
    int t = threadIdx.x;
    // stage Wm2T -> LDS with 16B-unit XOR swizzle: phys_unit = n*16 + (k16 ^ (n&15))
    for (int u = t; u < 1024; u += 256) {
        int n = u >> 4, k16 = u & 15;
        int phys = (n << 4) | (k16 ^ (n & 15));
        *(bf16x8*)(sW + phys * 8) = *(const bf16x8*)(Wm2T + n * 128 + k16 * 8);
    }
    int lane = t & 63;
    int lm = lane & 15, quad = lane >> 4;
    float bv[4], w30[4], w31[4];
#pragma unroll
    for (int nt = 0; nt < 4; nt++) {
        int n = nt * 16 + lm;
        bv[nt] = bm2[n]; w30[nt] = Wm3[2 * n]; w31[nt] = Wm3[2 * n + 1];
    }
    float b30 = bm3[0], b31 = bm3[1];
    __syncthreads();

    int gw = (blockIdx.x * blockDim.x + t) >> 6;
    int nw = (gridDim.x * blockDim.x) >> 6;

    for (int tile = gw; tile < E_ / 16; tile += nw) {
        int p0 = tile * 16;
        int sI = srcv[p0 + lm];
        int dI = (int)dstv[p0 + lm];
        const short* pr = Pb + (size_t)sI * 128 + quad * 8;
        const short* qr = Qb + (size_t)dI * 128 + quad * 8;
        // issue all 8 gathers up-front (latency hidden within wave)
        uint4 pu[4], qu[4];
#pragma unroll
        for (int kt = 0; kt < 4; kt++) {
            pu[kt] = *(const uint4*)(pr + kt * 32);
            qu[kt] = *(const uint4*)(qr + kt * 32);
        }
        bf16x8 aF[4];
#pragma unroll
        for (int kt = 0; kt < 4; kt++) {
            unsigned int pv[4] = {pu[kt].x, pu[kt].y, pu[kt].z, pu[kt].w};
            unsigned int qv[4] = {qu[kt].x, qu[kt].y, qu[kt].z, qu[kt].w};
            union { uint4 u; bf16x8 v; } cv;
            unsigned int rr[4];
#pragma unroll
            for (int j = 0; j < 4; j++) {
                float fl = fmaxf(bflo(pv[j]) + bflo(qv[j]), 0.f);
                float fh = fmaxf(bfhi(pv[j]) + bfhi(qv[j]), 0.f);
                rr[j] = (unsigned int)(unsigned short)f2bf(fl) |
                        ((unsigned int)(unsigned short)f2bf(fh) << 16);
            }
            cv.u.x = rr[0]; cv.u.y = rr[1]; cv.u.z = rr[2]; cv.u.w = rr[3];
            aF[kt] = cv.v;
        }
        float pz0[4] = {0.f, 0.f, 0.f, 0.f};
        float pz1[4] = {0.f, 0.f, 0.f, 0.f};
#pragma unroll
        for (int nt = 0; nt < 4; nt++) {
            floatx4 acc = (floatx4){0.f, 0.f, 0.f, 0.f};
#pragma unroll
            for (int kt = 0; kt < 4; kt++) {
                int phys = ((nt * 16 + lm) << 4) | (((kt << 2) | quad) ^ lm);
                bf16x8 bF = *(const bf16x8*)(sW + phys * 8);
                acc = __builtin_amdgcn_mfma_f32_16x16x32_bf16(aF[kt], bF, acc, 0, 0, 0);
            }
#pragma unroll
            for (int r = 0; r < 4; r++) {
                float u = fmaxf(acc[r] + bv[nt], 0.f);
                pz0[r] += u * w30[nt];
                pz1[r] += u * w31[nt];
            }
        }
#pragma unroll
        for (int off = 1; off < 16; off <<= 1) {
#pragma unroll
            for (int r = 0; r < 4; r++) {
                pz0[r] += __shfl_xor(pz0[r], off);
                pz1[r] += __shfl_xor(pz1[r], off);
            }
        }
        if (lm < 4) {
            int eid = eidv[p0 + quad * 4 + lm];
            float z0 = pz0[lm] + b30;
            float z1 = pz1[lm] + b31;
            if (isinf(z0)) z0 = 1e9f;
            if (isinf(z1)) z1 = 1e9f;
            *(float2*)(zout + (size_t)eid * 2) = make_float2(z0, z1);
        }
    }
}

extern "C" void kernel_launch(void* const* d_in, const int* in_sizes, int n_in,
                              void* d_out, int out_size, void* d_ws, size_t ws_size,
                              hipStream_t stream) {
    const float* h_in  = (const float*)d_in[0];
    const int*   src   = (const int*)d_in[2];
    const int*   dst   = (const int*)d_in[3];
    const float* W_emb = (const float*)d_in[4];
    const float* b_emb = (const float*)d_in[5];
    const float* Wg    = (const float*)d_in[6];
    const float* alg   = (const float*)d_in[7];
    const float* arg_  = (const float*)d_in[8];
    const float* bg    = (const float*)d_in[9];
    const float* gam   = (const float*)d_in[10];
    const float* bet   = (const float*)d_in[11];
    const float* W3    = (const float*)d_in[12];
    const float* al3   = (const float*)d_in[13];
    const float* ar3   = (const float*)d_in[14];
    const float* b3    = (const float*)d_in[15];
    const float* gam3  = (const float*)d_in[16];
    const float* bet3  = (const float*)d_in[17];
    const float* Wa    = (const float*)d_in[18];
    const float* ba    = (const float*)d_in[19];
    const float* Wm1   = (const float*)d_in[20];
    const float* bm1   = (const float*)d_in[21];
    const float* Wm2   = (const float*)d_in[22];
    const float* bm2   = (const float*)d_in[23];
    const float* Wm3   = (const float*)d_in[24];
    const float* bm3   = (const float*)d_in[25];

    float* zout = (float*)d_out;
    float* sout = zout + (size_t)E_ * 2;

    float* ws = (float*)d_ws;
    size_t o = 0;
    float* h_cur = ws + o; o += (size_t)N_ * 128;
    float* xbuf  = ws + o; o += (size_t)N_ * 128;
    float* featb = ws + o; o += (size_t)N_ * 128;   // reused: bf16 feat, coarse partials, bf16 P/Q
    float* el    = ws + o; o += (size_t)N_ * 8;
    float* er    = ws + o; o += (size_t)N_ * 8;
    float* colsum = ws + o; o += 128;
    float* colsq  = ws + o; o += 128;
    float* hc     = ws + o; o += 100 * 128;
    short* Wm2T = (short*)(ws + o); o += (64 * 128) / 2;
    short* WbT6 = (short*)(ws + o); o += (6 * 16384) / 2;
    short* WembT_hi = (short*)(ws + o); o += 16384 / 2;
    short* WembT_lo = (short*)(ws + o); o += 16384 / 2;
    short* WaT_hi   = (short*)(ws + o); o += 16384 / 2;
    short* WaT_lo   = (short*)(ws + o); o += 16384 / 2;
    int* counts = (int*)(ws + o); o += N_;
    int* rowptr = (int*)(ws + o); o += N_ + 4;
    int* cursor = (int*)(ws + o); o += N_;
    int* srcv   = (int*)(ws + o); o += E_;
    unsigned short* dstv = (unsigned short*)(ws + o); o += E_ / 2;
    int* eidv   = (int*)(ws + o); o += E_;
    int* bsum   = (int*)(ws + o); o += SNB_ + 4;

    short* featw = (short*)featb;  // bf16 per-layer projection

    // ---- CSR build (parallel scan; excl scratch reuses eidv pre-fill) ----
    hipMemsetAsync(counts, 0, N_ * sizeof(int), stream);
    k_count<<<1024, 256, 0, stream>>>(dst, counts);
    k_scanA<<<SNB_, 256, 0, stream>>>(counts, eidv, bsum);
    k_scanB<<<1, 256, 0, stream>>>(bsum);
    k_scanC<<<SNB_ + 1, 256, 0, stream>>>(eidv, bsum, rowptr, cursor);
    k_fill<<<1024, 256, 0, stream>>>(src, dst, cursor, srcv, dstv, eidv);
    k_prep_w<<<32, 256, 0, stream>>>(Wm2, Wm2T);
    k_prep_all<<<384, 256, 0, stream>>>(Wg, W3, Wm1, WbT6);
    k_prep_hilo<<<128, 256, 0, stream>>>(W_emb, Wa, WembT_hi, WembT_lo, WaT_hi, WaT_lo);

    // ---- embedding (fp32-accurate via hi/lo MFMA) ----
    k_mfma_hilo<<<N_ / 64, 256, 0, stream>>>(h_in, WembT_hi, WembT_lo, b_emb, h_cur, 128);

    // ---- layer 0 (H=8) ----
    k_gemm_mfma<<<N_ / 64, 256, 0, stream>>>(h_cur, WbT6 + 0 * 16384, nullptr, featw);
    k_elr<8><<<N_ / 4, 256, 0, stream>>>(featw, alg + 0 * 128, arg_ + 0 * 128, el, er);
    hipMemsetAsync(colsum, 0, 256 * sizeof(float), stream);
    k_gat_agg<8><<<2048, 256, 0, stream>>>(featw, el, er, rowptr, srcv, bg + 0 * 128, xbuf,
                                           colsum, colsq);
    k_bn_apply<<<(N_ * 128) / 256, 256, 0, stream>>>(xbuf, h_cur, colsum, colsq,
                                                     gam + 0 * 128, bet + 0 * 128, h_cur, 1);

    // ---- layer 1 (biGAT, H=8) ----
    k_mfma_hilo<<<N_ / 64, 256, 0, stream>>>(h_cur, WaT_hi, WaT_lo, ba, xbuf, 100);
    k_smax100<<<N_ / 4, 256, 0, stream>>>(xbuf, sout);
    k_gemm_mfma<<<N_ / 64, 256, 0, stream>>>(h_cur, WbT6 + 1 * 16384, nullptr, featw);
    k_elr<8><<<N_ / 4, 256, 0, stream>>>(featw, alg + 1 * 128, arg_ + 1 * 128, el, er);
    hipMemsetAsync(colsum, 0, 256 * sizeof(float), stream);
    k_gat_agg<8><<<2048, 256, 0, stream>>>(featw, el, er, rowptr, srcv, bg + 1 * 128, xbuf,
                                           colsum, colsq);
    k_bn_apply<<<(N_ * 128) / 256, 256, 0, stream>>>(xbuf, h_cur, colsum, colsq,
                                                     gam + 1 * 128, bet + 1 * 128, xbuf, 0);
    k_coarse_part<<<CB_, 512, 0, stream>>>(sout, xbuf, featb);
    k_coarse_reduce<<<50, 256, 0, stream>>>(featb, hc);
    k_combine<<<N_ / 16, 256, 0, stream>>>(sout, hc, xbuf, h_cur);

    // ---- layer 2 (H=8) ----
    k_gemm_mfma<<<N_ / 64, 256, 0, stream>>>(h_cur, WbT6 + 2 * 16384, nullptr, featw);
    k_elr<8><<<N_ / 4, 256, 0, stream>>>(featw, alg + 2 * 128, arg_ + 2 * 128, el, er);
    hipMemsetAsync(colsum, 0, 256 * sizeof(float), stream);
    k_gat_agg<8><<<2048, 256, 0, stream>>>(featw, el, er, rowptr, srcv, bg + 2 * 128, xbuf,
                                           colsum, colsq);
    k_bn_apply<<<(N_ * 128) / 256, 256, 0, stream>>>(xbuf, h_cur, colsum, colsq,
                                                     gam + 2 * 128, bet + 2 * 128, h_cur, 1);

    // ---- layer 3 (H=1) ----
    k_gemm_mfma<<<N_ / 64, 256, 0, stream>>>(h_cur, WbT6 + 3 * 16384, nullptr, featw);
    k_elr<1><<<N_ / 4, 256, 0, stream>>>(featw, al3, ar3, el, er);
    hipMemsetAsync(colsum, 0, 256 * sizeof(float), stream);
    k_gat_agg<1><<<2048, 256, 0, stream>>>(featw, el, er, rowptr, srcv, b3, xbuf,
                                           colsum, colsq);
    k_bn_apply<<<(N_ * 128) / 256, 256, 0, stream>>>(xbuf, h_cur, colsum, colsq,
                                                     gam3, bet3, h_cur, 1);

    // ---- edge MLP readout: Pb = bf16(h@Wm1[:128]+bm1), Qb = bf16(h@Wm1[128:]) ----
    short* Pb = (short*)featb;
    short* Qb = Pb + (size_t)N_ * 128;
    k_gemm_mfma<<<N_ / 64, 256, 0, stream>>>(h_cur, WbT6 + 4 * 16384, bm1, Pb);
    k_gemm_mfma<<<N_ / 64, 256, 0, stream>>>(h_cur, WbT6 + 5 * 16384, nullptr, Qb);
    k_edge_mlp3<<<2048, 256, 0, stream>>>(Pb, Qb, srcv, dstv, eidv, Wm2T, bm2, Wm3, bm3, zout);
}

// Round 8
// 832.096 us; speedup vs baseline: 1.2817x; 1.2817x over previous
//
#include <hip/hip_runtime.h>
#include <hip/hip_bf16.h>
#include <math.h>

#define N_ 40000
#define E_ 640000
#define CB_ 400   // k_coarse partial blocks
#define CR_ 100   // rows per block (CB_*CR_ == N_)
#define SB_ 256
#define SNB_ 157  // ceil(N_/SB_)

typedef short bf16x8 __attribute__((ext_vector_type(8)));
typedef float floatx4 __attribute__((ext_vector_type(4)));

__device__ __forceinline__ short f2bf(float f) {
    __hip_bfloat16 h = __float2bfloat16(f);
    return *reinterpret_cast<short*>(&h);
}
__device__ __forceinline__ float bf2f(short u) {
    unsigned int x = ((unsigned int)(unsigned short)u) << 16;
    return __int_as_float(x);
}
__device__ __forceinline__ float rdlane(float v, int l) {
    return __int_as_float(__builtin_amdgcn_readlane(__float_as_int(v), l));
}
// unpack 2 bf16 packed in a uint
__device__ __forceinline__ float bflo(unsigned int u) { return __int_as_float(u << 16); }
__device__ __forceinline__ float bfhi(unsigned int u) { return __int_as_float(u & 0xffff0000u); }

// ---------------- CSR build ----------------
__global__ void k_count(const int* __restrict__ dst, int* __restrict__ counts) {
    for (int e = blockIdx.x * blockDim.x + threadIdx.x; e < E_; e += gridDim.x * blockDim.x)
        atomicAdd(&counts[dst[e]], 1);
}

// ---- 3-phase parallel scan ----
__global__ __launch_bounds__(256) void k_scanA(const int* __restrict__ counts,
                                               int* __restrict__ excl,
                                               int* __restrict__ bsum) {
    int t = threadIdx.x;
    int i = blockIdx.x * SB_ + t;
    int v = (i < N_) ? counts[i] : 0;
    int lane = t & 63, wv = t >> 6;
    int x = v;
#pragma unroll
    for (int off = 1; off < 64; off <<= 1) {
        int y = __shfl_up(x, off);
        if (lane >= off) x += y;
    }
    __shared__ int wsum[4];
    __shared__ int woff[4];
    if (lane == 63) wsum[wv] = x;
    __syncthreads();
    if (t == 0) {
        int a = 0;
#pragma unroll
        for (int j = 0; j < 4; j++) { int tv = wsum[j]; woff[j] = a; a += tv; }
        bsum[blockIdx.x] = a;
    }
    __syncthreads();
    if (i < N_) excl[i] = x - v + woff[wv];
}

__global__ __launch_bounds__(256) void k_scanB(int* __restrict__ bsum) {
    int t = threadIdx.x;
    int v = (t < SNB_) ? bsum[t] : 0;
    int lane = t & 63, wv = t >> 6;
    int x = v;
#pragma unroll
    for (int off = 1; off < 64; off <<= 1) {
        int y = __shfl_up(x, off);
        if (lane >= off) x += y;
    }
    __shared__ int wsum[4];
    __shared__ int woff[4];
    if (lane == 63) wsum[wv] = x;
    __syncthreads();
    if (t == 0) {
        int a = 0;
#pragma unroll
        for (int j = 0; j < 4; j++) { int tv = wsum[j]; woff[j] = a; a += tv; }
    }
    __syncthreads();
    if (t < SNB_) bsum[t] = x - v + woff[wv];
}

__global__ __launch_bounds__(256) void k_scanC(const int* __restrict__ excl,
                                               const int* __restrict__ bsum,
                                               int* __restrict__ rowptr,
                                               int* __restrict__ cursor) {
    int i = blockIdx.x * 256 + threadIdx.x;
    if (i < N_) {
        int r = excl[i] + bsum[i / SB_];
        rowptr[i] = r;
        cursor[i] = r;
    }
    if (i == N_) rowptr[N_] = E_;
}

__global__ void k_fill(const int* __restrict__ src, const int* __restrict__ dst,
                       int* __restrict__ cursor, int* __restrict__ srcv,
                       unsigned short* __restrict__ dstv, int* __restrict__ eidv) {
    for (int e = blockIdx.x * blockDim.x + threadIdx.x; e < E_; e += gridDim.x * blockDim.x) {
        int d = dst[e];
        int pos = atomicAdd(&cursor[d], 1);
        srcv[pos] = src[e];
        dstv[pos] = (unsigned short)d;
        eidv[pos] = e;
    }
}

// ---------------- prep: 6x fp32 [k=128][n=128] -> bf16 [n][k] ----------------
__global__ __launch_bounds__(256) void k_prep_all(const float* __restrict__ Wg,
                                                  const float* __restrict__ W3,
                                                  const float* __restrict__ Wm1,
                                                  short* __restrict__ WbT6) {
    int i = blockIdx.x * 256 + threadIdx.x;   // 6*16384 total
    if (i >= 6 * 16384) return;
    int m = i >> 14;
    int r = i & 16383;
    int n = r >> 7, k = r & 127;
    const float* srcp;
    switch (m) {
        case 0: srcp = Wg; break;
        case 1: srcp = Wg + 16384; break;
        case 2: srcp = Wg + 32768; break;
        case 3: srcp = W3; break;
        case 4: srcp = Wm1; break;
        default: srcp = Wm1 + 16384; break;
    }
    WbT6[m * 16384 + n * 128 + k] = f2bf(srcp[k * 128 + n]);
}

// ---------------- prep: hi/lo bf16 splits of W_emb [128,128] and Wa [128,100] ----------------
// outputs transposed [n][k]; Wa zero-padded to n=128
__global__ __launch_bounds__(256) void k_prep_hilo(const float* __restrict__ W_emb,
                                                   const float* __restrict__ Wa,
                                                   short* __restrict__ WembT_hi,
                                                   short* __restrict__ WembT_lo,
                                                   short* __restrict__ WaT_hi,
                                                   short* __restrict__ WaT_lo) {
    int i = blockIdx.x * 256 + threadIdx.x;   // 2*16384 total
    if (i >= 2 * 16384) return;
    int m = i >> 14;
    int r = i & 16383;
    int n = r >> 7, k = r & 127;
    if (m == 0) {
        float w = W_emb[k * 128 + n];
        short h = f2bf(w);
        WembT_hi[n * 128 + k] = h;
        WembT_lo[n * 128 + k] = f2bf(w - bf2f(h));
    } else {
        float w = (n < 100) ? Wa[k * 100 + n] : 0.f;
        short h = f2bf(w);
        WaT_hi[n * 128 + k] = h;
        WaT_lo[n * 128 + k] = f2bf(w - bf2f(h));
    }
}

// ---------------- fp32-accurate MFMA GEMM via 3-term hi/lo split ----------------
// C[64rows x ncols] = A(fp32) @ B(fp32 decomposed as bf16 hi+lo), fp32 out.
// C = Ah@Bh + Al@Bh + Ah@Bl  (dropped Al@Bl ~ 2^-16 relative).
// A hi/lo staged in LDS; B_hi in LDS; B_lo fragments read from global (32KB, L2-resident).
__global__ __launch_bounds__(256) void k_mfma_hilo(const float* __restrict__ A,
                                                   const short* __restrict__ BT_hi,
                                                   const short* __restrict__ BT_lo,
                                                   const float* __restrict__ bias,
                                                   float* __restrict__ C, int ncols) {
    __shared__ short sAh[64 * 136];
    __shared__ short sAl[64 * 136];
    __shared__ short sBh[128 * 136];
    int t = threadIdx.x;
    int r0 = blockIdx.x * 64;
    // stage B_hi: each thread copies 64 bf16
    {
        int n = t >> 1;
        int k0 = (t & 1) * 64;
#pragma unroll
        for (int j = 0; j < 8; j++) {
            bf16x8 v = *(const bf16x8*)(BT_hi + n * 128 + k0 + 8 * j);
            *(bf16x8*)(sBh + n * 136 + k0 + 8 * j) = v;
        }
    }
    // stage A hi/lo: each thread converts 32 floats
    {
        int r = t >> 2;
        int k0 = (t & 3) * 32;
        const float* ar = A + (size_t)(r0 + r) * 128 + k0;
#pragma unroll
        for (int j = 0; j < 4; j++) {
            float4 f0 = *(const float4*)(ar + 8 * j);
            float4 f1 = *(const float4*)(ar + 8 * j + 4);
            float x[8] = {f0.x, f0.y, f0.z, f0.w, f1.x, f1.y, f1.z, f1.w};
            bf16x8 vh, vl;
#pragma unroll
            for (int q = 0; q < 8; q++) {
                short hh = f2bf(x[q]);
                vh[q] = hh;
                vl[q] = f2bf(x[q] - bf2f(hh));
            }
            *(bf16x8*)(sAh + r * 136 + k0 + 8 * j) = vh;
            *(bf16x8*)(sAl + r * 136 + k0 + 8 * j) = vl;
        }
    }
    __syncthreads();
    int lane = t & 63, wv = t >> 6;
    int lm = lane & 15, quad = lane >> 4;
    int m0 = wv * 16;
    bf16x8 aH[4], aL[4];
#pragma unroll
    for (int kt = 0; kt < 4; kt++) {
        aH[kt] = *(const bf16x8*)(sAh + (m0 + lm) * 136 + kt * 32 + quad * 8);
        aL[kt] = *(const bf16x8*)(sAl + (m0 + lm) * 136 + kt * 32 + quad * 8);
    }
#pragma unroll
    for (int nt = 0; nt < 8; nt++) {
        const short* blp = BT_lo + (nt * 16 + lm) * 128 + quad * 8;
        floatx4 acc = (floatx4){0.f, 0.f, 0.f, 0.f};
#pragma unroll
        for (int kt = 0; kt < 4; kt++) {
            bf16x8 bH = *(const bf16x8*)(sBh + (nt * 16 + lm) * 136 + kt * 32 + quad * 8);
            bf16x8 bL = *(const bf16x8*)(blp + kt * 32);
            acc = __builtin_amdgcn_mfma_f32_16x16x32_bf16(aH[kt], bH, acc, 0, 0, 0);
            acc = __builtin_amdgcn_mfma_f32_16x16x32_bf16(aL[kt], bH, acc, 0, 0, 0);
            acc = __builtin_amdgcn_mfma_f32_16x16x32_bf16(aH[kt], bL, acc, 0, 0, 0);
        }
        int col = nt * 16 + lm;
        if (col < ncols) {
            float bv = bias ? bias[col] : 0.f;
#pragma unroll
            for (int r = 0; r < 4; r++) {
                int row = r0 + m0 + quad * 4 + r;
                C[(size_t)row * ncols + col] = acc[r] + bv;
            }
        }
    }
}

// ---------------- MFMA GEMM: [N,128](fp32) @ WbT(bf16 [n][k]) -> bf16 out ----------------
// 64 rows/block, full N=128. A converted fp32->bf16 into LDS (+8 pad = 2-way bank, free).
__global__ __launch_bounds__(256) void k_gemm_mfma(const float* __restrict__ A,
                                                   const short* __restrict__ WbT,
                                                   const float* __restrict__ bias,
                                                   short* __restrict__ C) {
    __shared__ short sA[64 * 136];
    __shared__ short sB[128 * 136];
    int t = threadIdx.x;
    int r0 = blockIdx.x * 64;
    // stage B: each thread copies 64 bf16
    {
        int n = t >> 1;
        int k0 = (t & 1) * 64;
#pragma unroll
        for (int j = 0; j < 8; j++) {
            bf16x8 v = *(const bf16x8*)(WbT + n * 128 + k0 + 8 * j);
            *(bf16x8*)(sB + n * 136 + k0 + 8 * j) = v;
        }
    }
    // stage A: each thread converts 32 floats
    {
        int r = t >> 2;
        int k0 = (t & 3) * 32;
        const float* ar = A + (size_t)(r0 + r) * 128 + k0;
#pragma unroll
        for (int j = 0; j < 4; j++) {
            float4 f0 = *(const float4*)(ar + 8 * j);
            float4 f1 = *(const float4*)(ar + 8 * j + 4);
            bf16x8 v;
            v[0] = f2bf(f0.x); v[1] = f2bf(f0.y); v[2] = f2bf(f0.z); v[3] = f2bf(f0.w);
            v[4] = f2bf(f1.x); v[5] = f2bf(f1.y); v[6] = f2bf(f1.z); v[7] = f2bf(f1.w);
            *(bf16x8*)(sA + r * 136 + k0 + 8 * j) = v;
        }
    }
    __syncthreads();
    int lane = t & 63, wv = t >> 6;
    int lm = lane & 15, quad = lane >> 4;
    int m0 = wv * 16;
    bf16x8 aF[4];
#pragma unroll
    for (int kt = 0; kt < 4; kt++)
        aF[kt] = *(const bf16x8*)(sA + (m0 + lm) * 136 + kt * 32 + quad * 8);
#pragma unroll
    for (int nt = 0; nt < 8; nt++) {
        floatx4 acc = (floatx4){0.f, 0.f, 0.f, 0.f};
#pragma unroll
        for (int kt = 0; kt < 4; kt++) {
            bf16x8 bF = *(const bf16x8*)(sB + (nt * 16 + lm) * 136 + kt * 32 + quad * 8);
            acc = __builtin_amdgcn_mfma_f32_16x16x32_bf16(aF[kt], bF, acc, 0, 0, 0);
        }
        int col = nt * 16 + lm;
        float bv = bias ? bias[col] : 0.f;
#pragma unroll
        for (int r = 0; r < 4; r++) {
            int row = r0 + m0 + quad * 4 + r;
            C[(size_t)row * 128 + col] = f2bf(acc[r] + bv);
        }
    }
}

// ---------------- softmax over 100 logits, wave per node, barrier-free ----------------
__global__ __launch_bounds__(256) void k_smax100(const float* __restrict__ logits,
                                                 float* __restrict__ s) {
    int lane = threadIdx.x & 63;
    int n = blockIdx.x * 4 + (threadIdx.x >> 6);
    if (n >= N_) return;
    bool act = lane < 50;
    float2 v = make_float2(-INFINITY, -INFINITY);
    if (act) v = *(const float2*)(logits + (size_t)n * 100 + 2 * lane);
    float mx = fmaxf(v.x, v.y);
#pragma unroll
    for (int off = 1; off < 64; off <<= 1) mx = fmaxf(mx, __shfl_xor(mx, off));
    float e0 = act ? __expf(v.x - mx) : 0.f;
    float e1 = act ? __expf(v.y - mx) : 0.f;
    float sm = e0 + e1;
#pragma unroll
    for (int off = 1; off < 64; off <<= 1) sm += __shfl_xor(sm, off);
    float inv = 1.f / sm;
    if (act) *(float2*)(s + (size_t)n * 100 + 2 * lane) = make_float2(e0 * inv, e1 * inv);
}

// ---------------- per-node attention logits el/er (bf16 feat) ----------------
template <int H>
__global__ __launch_bounds__(256) void k_elr(const short* __restrict__ feat,
                                             const float* __restrict__ al,
                                             const float* __restrict__ ar,
                                             float* __restrict__ el, float* __restrict__ er) {
    int lane = threadIdx.x & 63;
    int n = blockIdx.x * 4 + (threadIdx.x >> 6);
    if (n >= N_) return;
    unsigned int u = *(const unsigned int*)(feat + (size_t)n * 128 + 2 * lane);
    float fx = bflo(u), fy = bfhi(u);
    float2 a = *(const float2*)(al + 2 * lane);
    float2 b = *(const float2*)(ar + 2 * lane);
    float pl = fx * a.x + fy * a.y;
    float pr = fx * b.x + fy * b.y;
    constexpr int G = 64 / H;
#pragma unroll
    for (int off = 1; off < G; off <<= 1) {
        pl += __shfl_xor(pl, off);
        pr += __shfl_xor(pr, off);
    }
    if ((lane & (G - 1)) == 0) {
        int hh = lane / G;
        el[(size_t)n * H + hh] = pl;
        er[(size_t)n * H + hh] = pr;
    }
}

// ---------------- GAT edge-softmax + aggregate (wave per dst node, bf16 feat) ----------------
// v4 (proven 824us config — REVERTED from v5: fused BN-stats atomic epilogue created a
// 2048-way contended atomic burst with nothing to overlap (~70us tail), and the pass-1
// interleave rewrite broke the compiler's own srcv prefetch pipelining. Do not re-fuse
// stats into this kernel with global atomics.)
template <int H>
__global__ __launch_bounds__(256) void k_gat_agg(const short* __restrict__ feat,
                                                 const float* __restrict__ el,
                                                 const float* __restrict__ er,
                                                 const int* __restrict__ rowptr,
                                                 const int* __restrict__ srcv,
                                                 const float* __restrict__ bias,
                                                 float* __restrict__ xout) {
    int lane = threadIdx.x & 63;
    int gw = (blockIdx.x * blockDim.x + threadIdx.x) >> 6;
    int nw = (gridDim.x * blockDim.x) >> 6;
    constexpr int LH = (H == 8) ? 3 : 0;
    int h = lane & (H - 1);
    int f0 = 2 * lane;
    int hf = (H == 8) ? (lane >> 3) : 0;   // head owning this lane's feature slice

    for (int n = gw; n < N_; n += nw) {
        int beg = rowptr[n], end = rowptr[n + 1];
        if (beg == end) {
            *(float2*)(xout + (size_t)n * 128 + f0) = *(const float2*)(bias + f0);
            continue;
        }
        float ern = er[(size_t)n * H + h];
        // ---- pass 1: online softmax stats ----
        float m = -INFINITY, ss = 0.f;
        for (int e = beg + (lane >> LH); e < end; e += (64 >> LH)) {
            int sI = srcv[e];
            float x = el[(size_t)sI * H + h] + ern;
            float lr = x > 0.f ? x : 0.2f * x;
            if (lr > m) { ss = ss * __expf(m - lr) + 1.f; m = lr; }
            else ss += __expf(lr - m);
        }
#pragma unroll
        for (int off = H; off < 64; off <<= 1) {
            float om = __shfl_xor(m, off);
            float os = __shfl_xor(ss, off);
            float nm = fmaxf(m, om);
            float p1 = (m == -INFINITY) ? 0.f : ss * __expf(m - nm);
            float p2 = (om == -INFINITY) ? 0.f : os * __expf(om - nm);
            m = nm; ss = p1 + p2;
        }
        // after butterfly each lane holds (m, ss) for its own head h = lane&(H-1)
        float inv_d = 1.f / ss;
        // ---- pass 2: 2x interleaved chunked aggregation ----
        int endm1 = end - 1;
        float accx = 0.f, accy = 0.f;
        for (int e0 = beg; e0 < end; e0 += 16) {
            int le = lane >> 3;
            int eLA = e0 + le, eLB = e0 + 8 + le;
            int eCA = eLA <= endm1 ? eLA : endm1;
            int eCB = eLB <= endm1 ? eLB : endm1;
            int sLA = srcv[eCA];
            int sLB = srcv[eCB];
            float xA = el[(size_t)sLA * H + h] + ern;
            float xB = el[(size_t)sLB * H + h] + ern;
            float lrA = xA > 0.f ? xA : 0.2f * xA;
            float lrB = xB > 0.f ? xB : 0.2f * xB;
            float wA = __expf(lrA - m) * inv_d;
            float wB = __expf(lrB - m) * inv_d;
            if (eLA > endm1) wA = 0.f;
            if (eLB > endm1) wB = 0.f;
            bool haveB = (e0 + 8) < end;    // wave-uniform
            unsigned int uuA[8], uuB[8];
#pragma unroll
            for (int j = 0; j < 8; j++) {
                int sj = __builtin_amdgcn_readlane(sLA, j * 8);
                uuA[j] = *(const unsigned int*)(feat + (size_t)sj * 128 + f0);
            }
            if (haveB) {
#pragma unroll
                for (int j = 0; j < 8; j++) {
                    int sj = __builtin_amdgcn_readlane(sLB, j * 8);
                    uuB[j] = *(const unsigned int*)(feat + (size_t)sj * 128 + f0);
                }
            }
#pragma unroll
            for (int j = 0; j < 8; j++) {
                float aj;
                if (H == 8) aj = __shfl(wA, j * 8 + hf);
                else        aj = rdlane(wA, j * 8);
                accx += aj * bflo(uuA[j]);
                accy += aj * bfhi(uuA[j]);
            }
            if (haveB) {
#pragma unroll
                for (int j = 0; j < 8; j++) {
                    float aj;
                    if (H == 8) aj = __shfl(wB, j * 8 + hf);
                    else        aj = rdlane(wB, j * 8);
                    accx += aj * bflo(uuB[j]);
                    accy += aj * bfhi(uuB[j]);
                }
            }
        }
        float2 b2 = *(const float2*)(bias + f0);
        *(float2*)(xout + (size_t)n * 128 + f0) = make_float2(accx + b2.x, accy + b2.y);
    }
}

// ---------------- BN stats ----------------
__global__ __launch_bounds__(256) void k_bn_stats(const float* __restrict__ x,
                                                  float* __restrict__ sum,
                                                  float* __restrict__ sumsq) {
    __shared__ float ls[256], lq[256];
    int t = threadIdx.x;
    int col = t & 127, half = t >> 7;
    float s = 0.f, q = 0.f;
    for (int r = blockIdx.x * 2 + half; r < N_; r += gridDim.x * 2) {
        float v = x[(size_t)r * 128 + col];
        s += v; q += v * v;
    }
    ls[t] = s; lq[t] = q;
    __syncthreads();
    if (t < 128) {
        atomicAdd(&sum[col], ls[t] + ls[t + 128]);
        atomicAdd(&sumsq[col], lq[t] + lq[t + 128]);
    }
}

// ---------------- BN apply + ELU + residual (+mask) ----------------
__global__ __launch_bounds__(256) void k_bn_apply(const float* __restrict__ x,
                                                  const float* __restrict__ hprev,
                                                  const float* __restrict__ sum,
                                                  const float* __restrict__ sumsq,
                                                  const float* __restrict__ g,
                                                  const float* __restrict__ b,
                                                  float* __restrict__ out, int do_mask) {
    int i = blockIdx.x * blockDim.x + threadIdx.x;
    if (i >= N_ * 128) return;
    int c = i & 127;
    const float invN = 1.f / (float)N_;
    float mu = sum[c] * invN;
    float var = sumsq[c] * invN - mu * mu;
    float inv = rsqrtf(var + 1e-5f);
    float y = g[c] * (x[i] - mu) * inv + b[c];
    y = y > 0.f ? y : (__expf(y) - 1.f);
    float hv = hprev[i] + y;
    if (do_mask && isinf(hv)) hv = 1e9f;
    out[i] = hv;
}

// ---------------- h_coarse partials ----------------
__global__ __launch_bounds__(512) void k_coarse_part(const float* __restrict__ s,
                                                     const float* __restrict__ hf,
                                                     float* __restrict__ part) {
    int t = threadIdx.x;
    int c = t & 127;
    int g = t >> 7;        // 0..3
    int lane = t & 63;
    float acc[25];
#pragma unroll
    for (int a = 0; a < 25; a++) acc[a] = 0.f;
    int n0 = blockIdx.x * CR_;
    for (int n = n0; n < n0 + CR_; n += 2) {
        float hv0 = hf[(size_t)n * 128 + c];
        float hv1 = hf[(size_t)(n + 1) * 128 + c];
        float sv0 = 0.f, sv1 = 0.f;
        if (lane < 25) {
            sv0 = s[(size_t)n * 100 + 25 * g + lane];
            sv1 = s[(size_t)(n + 1) * 100 + 25 * g + lane];
        }
#pragma unroll
        for (int a = 0; a < 25; ++a) {
            float a0 = rdlane(sv0, a);
            float a1 = rdlane(sv1, a);
            acc[a] += a0 * hv0 + a1 * hv1;
        }
    }
    float* dstp = part + (size_t)blockIdx.x * 12800 + (size_t)(25 * g) * 128 + c;
#pragma unroll
    for (int a = 0; a < 25; a++) dstp[a * 128] = acc[a];
}

// ---------------- reduce partials -> hc[100][128] ----------------
__global__ __launch_bounds__(256) void k_coarse_reduce(const float* __restrict__ part,
                                                       float* __restrict__ hc) {
    int i = blockIdx.x * blockDim.x + threadIdx.x;  // 12800 total
    if (i >= 12800) return;
    float s0 = 0.f, s1 = 0.f, s2 = 0.f, s3 = 0.f;
    for (int b = 0; b < CB_; b += 4) {
        s0 += part[(size_t)(b + 0) * 12800 + i];
        s1 += part[(size_t)(b + 1) * 12800 + i];
        s2 += part[(size_t)(b + 2) * 12800 + i];
        s3 += part[(size_t)(b + 3) * 12800 + i];
    }
    hc[i] = (s0 + s1) + (s2 + s3);
}

// ---------------- h = mask(0.5*h_fine + 0.5*(s@h_coarse)) ----------------
// v3: 16 nodes/block (hc reused 16x), s tile staged in LDS (6.4KB, coalesced),
// compute reads are same-address LDS broadcasts + coalesced hc loads.
__global__ __launch_bounds__(256) void k_combine(const float* __restrict__ s,
                                                 const float* __restrict__ hc,
                                                 const float* __restrict__ hfine,
                                                 float* __restrict__ hout) {
    __shared__ float ssh[16 * 100];
    int t = threadIdx.x;
    int n0 = blockIdx.x * 16;
    for (int u = t; u < 1600; u += 256) ssh[u] = s[(size_t)n0 * 100 + u];
    __syncthreads();
    int c = t & 127, g = t >> 7;
    float acc[8];
#pragma unroll
    for (int r = 0; r < 8; r++) acc[r] = 0.f;
    const float* hcp = hc + c;
    for (int a = 0; a < 100; a += 4) {
        float h0 = hcp[(a + 0) * 128];
        float h1 = hcp[(a + 1) * 128];
        float h2 = hcp[(a + 2) * 128];
        float h3 = hcp[(a + 3) * 128];
#pragma unroll
        for (int r = 0; r < 8; r++) {
            float4 sv = *(const float4*)(ssh + (g * 8 + r) * 100 + a);
            acc[r] += sv.x * h0 + sv.y * h1 + sv.z * h2 + sv.w * h3;
        }
    }
#pragma unroll
    for (int r = 0; r < 8; r++) {
        int row = n0 + g * 8 + r;
        float v = 0.5f * hfine[(size_t)row * 128 + c] + 0.5f * acc[r];
        if (isinf(v)) v = 1e9f;
        hout[(size_t)row * 128 + c] = v;
    }
}

// ---------------- prep: Wm2 [128][64] fp32 -> Wm2T bf16 [64][128] ----------------
__global__ __launch_bounds__(256) void k_prep_w(const float* __restrict__ Wm2,
                                                short* __restrict__ Wm2T) {
    int i = blockIdx.x * blockDim.x + threadIdx.x;  // 8192 total
    if (i >= 64 * 128) return;
    int n = i & 63, k = i >> 6;
    Wm2T[n * 128 + k] = f2bf(Wm2[k * 64 + n]);
}

// ---------------- edge MLP readout: dst-sorted order, barrier-free persistent MFMA ----------------
// v4: TWO 16-edge tiles per loop iteration — all 16 P/Q gathers (A+B) issued before
// either tile's compute; tile B's loads hide under tile A's convert+MFMA+reduce.
// VGPR ~120 expected (<128 cliff); NO launch-bounds cap (round-5 lesson: forcing
// occupancy caused scratch spills, 6x FETCH). Weights in 16KiB XOR-swizzled LDS.
__global__ __launch_bounds__(256) void k_edge_mlp3(const short* __restrict__ Pb,
                                                   const short* __restrict__ Qb,
                                                   const int* __restrict__ srcv,
                                                   const unsigned short* __restrict__ dstv,
                                                   const int* __restrict__ eidv,
                                                   const short* __restrict__ Wm2T,
                                                   const float* __restrict__ bm2,
                                                   const float* __restrict__ Wm3,
                                                   const float* __restrict__ bm3,
                                                   float* __restrict__ zout) {
    __shared__ short sW[64 * 128];  // 16 KiB
    int t = threadIdx.x;
    // stage Wm2T -> LDS with 16B-unit XOR swizzle: phys_unit = n*16 + (k16 ^ (n&15))
    for (int u = t; u < 1024; u += 256) {
        int n = u >> 4, k16 = u & 15;
        int phys = (n << 4) | (k16 ^ (n & 15));
        *(bf16x8*)(sW + phys * 8) = *(const bf16x8*)(Wm2T + n * 128 + k16 * 8);
    }
    int lane = t & 63;
    int lm = lane & 15, quad = lane >> 4;
    float bv[4], w30[4], w31[4];
#pragma unroll
    for (int nt = 0; nt < 4; nt++) {
        int n = nt * 16 + lm;
        bv[nt] = bm2[n]; w30[nt] = Wm3[2 * n]; w31[nt] = Wm3[2 * n + 1];
    }
    float b30 = bm3[0], b31 = bm3[1];
    __syncthreads();

    int gw = (blockIdx.x * blockDim.x + t) >> 6;
    int nw = (gridDim.x * blockDim.x) >> 6;

    for (int tp = gw; tp < E_ / 32; tp += nw) {
        int pA = tp * 32;
        int pB = pA + 16;
        int sA = srcv[pA + lm];
        int dA = (int)dstv[pA + lm];
        int sB = srcv[pB + lm];
        int dB = (int)dstv[pB + lm];
        const short* prA = Pb + (size_t)sA * 128 + quad * 8;
        const short* qrA = Qb + (size_t)dA * 128 + quad * 8;
        const short* prB = Pb + (size_t)sB * 128 + quad * 8;
        const short* qrB = Qb + (size_t)dB * 128 + quad * 8;
        // issue all 16 gathers up-front (tile B latency hides under tile A compute)
        uint4 puA[4], quA[4], puB[4], quB[4];
#pragma unroll
        for (int kt = 0; kt < 4; kt++) {
            puA[kt] = *(const uint4*)(prA + kt * 32);
            quA[kt] = *(const uint4*)(qrA + kt * 32);
        }
#pragma unroll
        for (int kt = 0; kt < 4; kt++) {
            puB[kt] = *(const uint4*)(prB + kt * 32);
            quB[kt] = *(const uint4*)(qrB + kt * 32);
        }
        // ---- tile A ----
        {
            bf16x8 aF[4];
#pragma unroll
            for (int kt = 0; kt < 4; kt++) {
                unsigned int pv[4] = {puA[kt].x, puA[kt].y, puA[kt].z, puA[kt].w};
                unsigned int qv[4] = {quA[kt].x, quA[kt].y, quA[kt].z, quA[kt].w};
                union { uint4 u; bf16x8 v; } cv;
                unsigned int rr[4];
#pragma unroll
                for (int j = 0; j < 4; j++) {
                    float fl = fmaxf(bflo(pv[j]) + bflo(qv[j]), 0.f);
                    float fh = fmaxf(bfhi(pv[j]) + bfhi(qv[j]), 0.f);
                    rr[j] = (unsigned int)(unsigned short)f2bf(fl) |
                            ((unsigned int)(unsigned short)f2bf(fh) << 16);
                }
                cv.u.x = rr[0]; cv.u.y = rr[1]; cv.u.z = rr[2]; cv.u.w = rr[3];
                aF[kt] = cv.v;
            }
            float pz0[4] = {0.f, 0.f, 0.f, 0.f};
            float pz1[4] = {0.f, 0.f, 0.f, 0.f};
#pragma unroll
            for (int nt = 0; nt < 4; nt++) {
                floatx4 acc = (floatx4){0.f, 0.f, 0.f, 0.f};
#pragma unroll
                for (int kt = 0; kt < 4; kt++) {
                    int phys = ((nt * 16 + lm) << 4) | (((kt << 2) | quad) ^ lm);
                    bf16x8 bF = *(const bf16x8*)(sW + phys * 8);
                    acc = __builtin_amdgcn_mfma_f32_16x16x32_bf16(aF[kt], bF, acc, 0, 0, 0);
                }
#pragma unroll
                for (int r = 0; r < 4; r++) {
                    float u = fmaxf(acc[r] + bv[nt], 0.f);
                    pz0[r] += u * w30[nt];
                    pz1[r] += u * w31[nt];
                }
            }
#pragma unroll
            for (int off = 1; off < 16; off <<= 1) {
#pragma unroll
                for (int r = 0; r < 4; r++) {
                    pz0[r] += __shfl_xor(pz0[r], off);
                    pz1[r] += __shfl_xor(pz1[r], off);
                }
            }
            if (lm < 4) {
                int eid = eidv[pA + quad * 4 + lm];
                float z0 = pz0[lm] + b30;
                float z1 = pz1[lm] + b31;
                if (isinf(z0)) z0 = 1e9f;
                if (isinf(z1)) z1 = 1e9f;
                *(float2*)(zout + (size_t)eid * 2) = make_float2(z0, z1);
            }
        }
        // ---- tile B ----
        {
            bf16x8 aF[4];
#pragma unroll
            for (int kt = 0; kt < 4; kt++) {
                unsigned int pv[4] = {puB[kt].x, puB[kt].y, puB[kt].z, puB[kt].w};
                unsigned int qv[4] = {quB[kt].x, quB[kt].y, quB[kt].z, quB[kt].w};
                union { uint4 u; bf16x8 v; } cv;
                unsigned int rr[4];
#pragma unroll
                for (int j = 0; j < 4; j++) {
                    float fl = fmaxf(bflo(pv[j]) + bflo(qv[j]), 0.f);
                    float fh = fmaxf(bfhi(pv[j]) + bfhi(qv[j]), 0.f);
                    rr[j] = (unsigned int)(unsigned short)f2bf(fl) |
                            ((unsigned int)(unsigned short)f2bf(fh) << 16);
                }
                cv.u.x = rr[0]; cv.u.y = rr[1]; cv.u.z = rr[2]; cv.u.w = rr[3];
                aF[kt] = cv.v;
            }
            float pz0[4] = {0.f, 0.f, 0.f, 0.f};
            float pz1[4] = {0.f, 0.f, 0.f, 0.f};
#pragma unroll
            for (int nt = 0; nt < 4; nt++) {
                floatx4 acc = (floatx4){0.f, 0.f, 0.f, 0.f};
#pragma unroll
                for (int kt = 0; kt < 4; kt++) {
                    int phys = ((nt * 16 + lm) << 4) | (((kt << 2) | quad) ^ lm);
                    bf16x8 bF = *(const bf16x8*)(sW + phys * 8);
                    acc = __builtin_amdgcn_mfma_f32_16x16x32_bf16(aF[kt], bF, acc, 0, 0, 0);
                }
#pragma unroll
                for (int r = 0; r < 4; r++) {
                    float u = fmaxf(acc[r] + bv[nt], 0.f);
                    pz0[r] += u * w30[nt];
                    pz1[r] += u * w31[nt];
                }
            }
#pragma unroll
            for (int off = 1; off < 16; off <<= 1) {
#pragma unroll
                for (int r = 0; r < 4; r++) {
                    pz0[r] += __shfl_xor(pz0[r], off);
                    pz1[r] += __shfl_xor(pz1[r], off);
                }
            }
            if (lm < 4) {
                int eid = eidv[pB + quad * 4 + lm];
                float z0 = pz0[lm] + b30;
                float z1 = pz1[lm] + b31;
                if (isinf(z0)) z0 = 1e9f;
                if (isinf(z1)) z1 = 1e9f;
                *(float2*)(zout + (size_t)eid * 2) = make_float2(z0, z1);
            }
        }
    }
}

extern "C" void kernel_launch(void* const* d_in, const int* in_sizes, int n_in,
                              void* d_out, int out_size, void* d_ws, size_t ws_size,
                              hipStream_t stream) {
    const float* h_in  = (const float*)d_in[0];
    const int*   src   = (const int*)d_in[2];
    const int*   dst   = (const int*)d_in[3];
    const float* W_emb = (const float*)d_in[4];
    const float* b_emb = (const float*)d_in[5];
    const float* Wg    = (const float*)d_in[6];
    const float* alg   = (const float*)d_in[7];
    const float* arg_  = (const float*)d_in[8];
    const float* bg    = (const float*)d_in[9];
    const float* gam   = (const float*)d_in[10];
    const float* bet   = (const float*)d_in[11];
    const float* W3    = (const float*)d_in[12];
    const float* al3   = (const float*)d_in[13];
    const float* ar3   = (const float*)d_in[14];
    const float* b3    = (const float*)d_in[15];
    const float* gam3  = (const float*)d_in[16];
    const float* bet3  = (const float*)d_in[17];
    const float* Wa    = (const float*)d_in[18];
    const float* ba    = (const float*)d_in[19];
    const float* Wm1   = (const float*)d_in[20];
    const float* bm1   = (const float*)d_in[21];
    const float* Wm2   = (const float*)d_in[22];
    const float* bm2   = (const float*)d_in[23];
    const float* Wm3   = (const float*)d_in[24];
    const float* bm3   = (const float*)d_in[25];

    float* zout = (float*)d_out;
    float* sout = zout + (size_t)E_ * 2;

    float* ws = (float*)d_ws;
    size_t o = 0;
    float* h_cur = ws + o; o += (size_t)N_ * 128;
    float* xbuf  = ws + o; o += (size_t)N_ * 128;
    float* featb = ws + o; o += (size_t)N_ * 128;   // reused: bf16 feat, coarse partials, bf16 P/Q
    float* el    = ws + o; o += (size_t)N_ * 8;
    float* er    = ws + o; o += (size_t)N_ * 8;
    float* colsum = ws + o; o += 128;
    float* colsq  = ws + o; o += 128;
    float* hc     = ws + o; o += 100 * 128;
    short* Wm2T = (short*)(ws + o); o += (64 * 128) / 2;
    short* WbT6 = (short*)(ws + o); o += (6 * 16384) / 2;
    short* WembT_hi = (short*)(ws + o); o += 16384 / 2;
    short* WembT_lo = (short*)(ws + o); o += 16384 / 2;
    short* WaT_hi   = (short*)(ws + o); o += 16384 / 2;
    short* WaT_lo   = (short*)(ws + o); o += 16384 / 2;
    int* counts = (int*)(ws + o); o += N_;
    int* rowptr = (int*)(ws + o); o += N_ + 4;
    int* cursor = (int*)(ws + o); o += N_;
    int* srcv   = (int*)(ws + o); o += E_;
    unsigned short* dstv = (unsigned short*)(ws + o); o += E_ / 2;
    int* eidv   = (int*)(ws + o); o += E_;
    int* bsum   = (int*)(ws + o); o += SNB_ + 4;

    short* featw = (short*)featb;  // bf16 per-layer projection

    // ---- CSR build (parallel scan; excl scratch reuses eidv pre-fill) ----
    hipMemsetAsync(counts, 0, N_ * sizeof(int), stream);
    k_count<<<1024, 256, 0, stream>>>(dst, counts);
    k_scanA<<<SNB_, 256, 0, stream>>>(counts, eidv, bsum);
    k_scanB<<<1, 256, 0, stream>>>(bsum);
    k_scanC<<<SNB_ + 1, 256, 0, stream>>>(eidv, bsum, rowptr, cursor);
    k_fill<<<1024, 256, 0, stream>>>(src, dst, cursor, srcv, dstv, eidv);
    k_prep_w<<<32, 256, 0, stream>>>(Wm2, Wm2T);
    k_prep_all<<<384, 256, 0, stream>>>(Wg, W3, Wm1, WbT6);
    k_prep_hilo<<<128, 256, 0, stream>>>(W_emb, Wa, WembT_hi, WembT_lo, WaT_hi, WaT_lo);

    // ---- embedding (fp32-accurate via hi/lo MFMA) ----
    k_mfma_hilo<<<N_ / 64, 256, 0, stream>>>(h_in, WembT_hi, WembT_lo, b_emb, h_cur, 128);

    // ---- layer 0 (H=8) ----
    k_gemm_mfma<<<N_ / 64, 256, 0, stream>>>(h_cur, WbT6 + 0 * 16384, nullptr, featw);
    k_elr<8><<<N_ / 4, 256, 0, stream>>>(featw, alg + 0 * 128, arg_ + 0 * 128, el, er);
    k_gat_agg<8><<<2048, 256, 0, stream>>>(featw, el, er, rowptr, srcv, bg + 0 * 128, xbuf);
    hipMemsetAsync(colsum, 0, 256 * sizeof(float), stream);
    k_bn_stats<<<512, 256, 0, stream>>>(xbuf, colsum, colsq);
    k_bn_apply<<<(N_ * 128) / 256, 256, 0, stream>>>(xbuf, h_cur, colsum, colsq,
                                                     gam + 0 * 128, bet + 0 * 128, h_cur, 1);

    // ---- layer 1 (biGAT, H=8) ----
    k_mfma_hilo<<<N_ / 64, 256, 0, stream>>>(h_cur, WaT_hi, WaT_lo, ba, xbuf, 100);
    k_smax100<<<N_ / 4, 256, 0, stream>>>(xbuf, sout);
    k_gemm_mfma<<<N_ / 64, 256, 0, stream>>>(h_cur, WbT6 + 1 * 16384, nullptr, featw);
    k_elr<8><<<N_ / 4, 256, 0, stream>>>(featw, alg + 1 * 128, arg_ + 1 * 128, el, er);
    k_gat_agg<8><<<2048, 256, 0, stream>>>(featw, el, er, rowptr, srcv, bg + 1 * 128, xbuf);
    hipMemsetAsync(colsum, 0, 256 * sizeof(float), stream);
    k_bn_stats<<<512, 256, 0, stream>>>(xbuf, colsum, colsq);
    k_bn_apply<<<(N_ * 128) / 256, 256, 0, stream>>>(xbuf, h_cur, colsum, colsq,
                                                     gam + 1 * 128, bet + 1 * 128, xbuf, 0);
    k_coarse_part<<<CB_, 512, 0, stream>>>(sout, xbuf, featb);
    k_coarse_reduce<<<50, 256, 0, stream>>>(featb, hc);
    k_combine<<<N_ / 16, 256, 0, stream>>>(sout, hc, xbuf, h_cur);

    // ---- layer 2 (H=8) ----
    k_gemm_mfma<<<N_ / 64, 256, 0, stream>>>(h_cur, WbT6 + 2 * 16384, nullptr, featw);
    k_elr<8><<<N_ / 4, 256, 0, stream>>>(featw, alg + 2 * 128, arg_ + 2 * 128, el, er);
    k_gat_agg<8><<<2048, 256, 0, stream>>>(featw, el, er, rowptr, srcv, bg + 2 * 128, xbuf);
    hipMemsetAsync(colsum, 0, 256 * sizeof(float), stream);
    k_bn_stats<<<512, 256, 0, stream>>>(xbuf, colsum, colsq);
    k_bn_apply<<<(N_ * 128) / 256, 256, 0, stream>>>(xbuf, h_cur, colsum, colsq,
                                                     gam + 2 * 128, bet + 2 * 128, h_cur, 1);

    // ---- layer 3 (H=1) ----
    k_gemm_mfma<<<N_ / 64, 256, 0, stream>>>(h_cur, WbT6 + 3 * 16384, nullptr, featw);
    k_elr<1><<<N_ / 4, 256, 0, stream>>>(featw, al3, ar3, el, er);
    k_gat_agg<1><<<2048, 256, 0, stream>>>(featw, el, er, rowptr, srcv, b3, xbuf);
    hipMemsetAsync(colsum, 0, 256 * sizeof(float), stream);
    k_bn_stats<<<512, 256, 0, stream>>>(xbuf, colsum, colsq);
    k_bn_apply<<<(N_ * 128) / 256, 256, 0, stream>>>(xbuf, h_cur, colsum, colsq,
                                                     gam3, bet3, h_cur, 1);

    // ---- edge MLP readout: Pb = bf16(h@Wm1[:128]+bm1), Qb = bf16(h@Wm1[128:]) ----
    short* Pb = (short*)featb;
    short* Qb = Pb + (size_t)N_ * 128;
    k_gemm_mfma<<<N_ / 64, 256, 0, stream>>>(h_cur, WbT6 + 4 * 16384, bm1, Pb);
    k_gemm_mfma<<<N_ / 64, 256, 0, stream>>>(h_cur, WbT6 + 5 * 16384, nullptr, Qb);
    k_edge_mlp3<<<2048, 256, 0, stream>>>(Pb, Qb, srcv, dstv, eidv, Wm2T, bm2, Wm3, bm3, zout);
}

// Round 9
// 811.852 us; speedup vs baseline: 1.3137x; 1.0249x over previous
//
#include <hip/hip_runtime.h>
#include <hip/hip_bf16.h>
#include <math.h>

#define N_ 40000
#define E_ 640000
#define CB_ 400   // k_coarse partial blocks
#define CR_ 100   // rows per block (CB_*CR_ == N_)
#define SB_ 256
#define SNB_ 157  // ceil(N_/SB_)

typedef short bf16x8 __attribute__((ext_vector_type(8)));
typedef float floatx4 __attribute__((ext_vector_type(4)));

__device__ __forceinline__ short f2bf(float f) {
    __hip_bfloat16 h = __float2bfloat16(f);
    return *reinterpret_cast<short*>(&h);
}
__device__ __forceinline__ float bf2f(short u) {
    unsigned int x = ((unsigned int)(unsigned short)u) << 16;
    return __int_as_float(x);
}
__device__ __forceinline__ float rdlane(float v, int l) {
    return __int_as_float(__builtin_amdgcn_readlane(__float_as_int(v), l));
}
// unpack 2 bf16 packed in a uint
__device__ __forceinline__ float bflo(unsigned int u) { return __int_as_float(u << 16); }
__device__ __forceinline__ float bfhi(unsigned int u) { return __int_as_float(u & 0xffff0000u); }

// ---------------- CSR build ----------------
__global__ void k_count(const int* __restrict__ dst, int* __restrict__ counts) {
    for (int e = blockIdx.x * blockDim.x + threadIdx.x; e < E_; e += gridDim.x * blockDim.x)
        atomicAdd(&counts[dst[e]], 1);
}

// ---- 3-phase parallel scan ----
__global__ __launch_bounds__(256) void k_scanA(const int* __restrict__ counts,
                                               int* __restrict__ excl,
                                               int* __restrict__ bsum) {
    int t = threadIdx.x;
    int i = blockIdx.x * SB_ + t;
    int v = (i < N_) ? counts[i] : 0;
    int lane = t & 63, wv = t >> 6;
    int x = v;
#pragma unroll
    for (int off = 1; off < 64; off <<= 1) {
        int y = __shfl_up(x, off);
        if (lane >= off) x += y;
    }
    __shared__ int wsum[4];
    __shared__ int woff[4];
    if (lane == 63) wsum[wv] = x;
    __syncthreads();
    if (t == 0) {
        int a = 0;
#pragma unroll
        for (int j = 0; j < 4; j++) { int tv = wsum[j]; woff[j] = a; a += tv; }
        bsum[blockIdx.x] = a;
    }
    __syncthreads();
    if (i < N_) excl[i] = x - v + woff[wv];
}

__global__ __launch_bounds__(256) void k_scanB(int* __restrict__ bsum) {
    int t = threadIdx.x;
    int v = (t < SNB_) ? bsum[t] : 0;
    int lane = t & 63, wv = t >> 6;
    int x = v;
#pragma unroll
    for (int off = 1; off < 64; off <<= 1) {
        int y = __shfl_up(x, off);
        if (lane >= off) x += y;
    }
    __shared__ int wsum[4];
    __shared__ int woff[4];
    if (lane == 63) wsum[wv] = x;
    __syncthreads();
    if (t == 0) {
        int a = 0;
#pragma unroll
        for (int j = 0; j < 4; j++) { int tv = wsum[j]; woff[j] = a; a += tv; }
    }
    __syncthreads();
    if (t < SNB_) bsum[t] = x - v + woff[wv];
}

__global__ __launch_bounds__(256) void k_scanC(const int* __restrict__ excl,
                                               const int* __restrict__ bsum,
                                               int* __restrict__ rowptr,
                                               int* __restrict__ cursor) {
    int i = blockIdx.x * 256 + threadIdx.x;
    if (i < N_) {
        int r = excl[i] + bsum[i / SB_];
        rowptr[i] = r;
        cursor[i] = r;
    }
    if (i == N_) rowptr[N_] = E_;
}

__global__ void k_fill(const int* __restrict__ src, const int* __restrict__ dst,
                       int* __restrict__ cursor, int* __restrict__ srcv,
                       unsigned short* __restrict__ dstv, int* __restrict__ eidv) {
    for (int e = blockIdx.x * blockDim.x + threadIdx.x; e < E_; e += gridDim.x * blockDim.x) {
        int d = dst[e];
        int pos = atomicAdd(&cursor[d], 1);
        srcv[pos] = src[e];
        dstv[pos] = (unsigned short)d;
        eidv[pos] = e;
    }
}

// ---------------- prep: 6x fp32 [k=128][n=128] -> bf16 [n][k] ----------------
__global__ __launch_bounds__(256) void k_prep_all(const float* __restrict__ Wg,
                                                  const float* __restrict__ W3,
                                                  const float* __restrict__ Wm1,
                                                  short* __restrict__ WbT6) {
    int i = blockIdx.x * 256 + threadIdx.x;   // 6*16384 total
    if (i >= 6 * 16384) return;
    int m = i >> 14;
    int r = i & 16383;
    int n = r >> 7, k = r & 127;
    const float* srcp;
    switch (m) {
        case 0: srcp = Wg; break;
        case 1: srcp = Wg + 16384; break;
        case 2: srcp = Wg + 32768; break;
        case 3: srcp = W3; break;
        case 4: srcp = Wm1; break;
        default: srcp = Wm1 + 16384; break;
    }
    WbT6[m * 16384 + n * 128 + k] = f2bf(srcp[k * 128 + n]);
}

// ---------------- prep: fused el/er weight tiles Wel[layer][16][128] ----------------
// el = (A@W)·al = A@(W@Aexp): Wel[n][k] = sum_d W[k][h*16+d]*a[h*16+d], h=n&7,
// a = al (n<8) or ar (n>=8). Layer 3 (H=1): n==0 -> W3·al3, n==1 -> W3·ar3, else 0.
__global__ __launch_bounds__(256) void k_prep_wela(const float* __restrict__ Wg,
                                                   const float* __restrict__ alg,
                                                   const float* __restrict__ arg_,
                                                   const float* __restrict__ W3,
                                                   const float* __restrict__ al3,
                                                   const float* __restrict__ ar3,
                                                   short* __restrict__ WelT) {
    int i = blockIdx.x * 256 + threadIdx.x;   // 4*16*128 = 8192 total
    if (i >= 4 * 2048) return;
    int layer = i >> 11;
    int r = i & 2047;
    int n = r >> 7, k = r & 127;
    float val = 0.f;
    if (layer < 3) {
        const float* W = Wg + layer * 16384;
        const float* a = (n < 8 ? alg : arg_) + layer * 128;
        int h = n & 7;
#pragma unroll
        for (int d = 0; d < 16; d++)
            val += W[k * 128 + h * 16 + d] * a[h * 16 + d];
    } else {
        if (n == 0) { for (int c = 0; c < 128; c++) val += W3[k * 128 + c] * al3[c]; }
        else if (n == 1) { for (int c = 0; c < 128; c++) val += W3[k * 128 + c] * ar3[c]; }
    }
    WelT[layer * 2048 + n * 128 + k] = f2bf(val);
}

// ---------------- prep: hi/lo bf16 splits of W_emb [128,128] and Wa [128,100] ----------------
// outputs transposed [n][k]; Wa zero-padded to n=128
__global__ __launch_bounds__(256) void k_prep_hilo(const float* __restrict__ W_emb,
                                                   const float* __restrict__ Wa,
                                                   short* __restrict__ WembT_hi,
                                                   short* __restrict__ WembT_lo,
                                                   short* __restrict__ WaT_hi,
                                                   short* __restrict__ WaT_lo) {
    int i = blockIdx.x * 256 + threadIdx.x;   // 2*16384 total
    if (i >= 2 * 16384) return;
    int m = i >> 14;
    int r = i & 16383;
    int n = r >> 7, k = r & 127;
    if (m == 0) {
        float w = W_emb[k * 128 + n];
        short h = f2bf(w);
        WembT_hi[n * 128 + k] = h;
        WembT_lo[n * 128 + k] = f2bf(w - bf2f(h));
    } else {
        float w = (n < 100) ? Wa[k * 100 + n] : 0.f;
        short h = f2bf(w);
        WaT_hi[n * 128 + k] = h;
        WaT_lo[n * 128 + k] = f2bf(w - bf2f(h));
    }
}

// ---------------- fp32-accurate MFMA GEMM via 3-term hi/lo split ----------------
__global__ __launch_bounds__(256) void k_mfma_hilo(const float* __restrict__ A,
                                                   const short* __restrict__ BT_hi,
                                                   const short* __restrict__ BT_lo,
                                                   const float* __restrict__ bias,
                                                   float* __restrict__ C, int ncols) {
    __shared__ short sAh[64 * 136];
    __shared__ short sAl[64 * 136];
    __shared__ short sBh[128 * 136];
    int t = threadIdx.x;
    int r0 = blockIdx.x * 64;
    // stage B_hi: each thread copies 64 bf16
    {
        int n = t >> 1;
        int k0 = (t & 1) * 64;
#pragma unroll
        for (int j = 0; j < 8; j++) {
            bf16x8 v = *(const bf16x8*)(BT_hi + n * 128 + k0 + 8 * j);
            *(bf16x8*)(sBh + n * 136 + k0 + 8 * j) = v;
        }
    }
    // stage A hi/lo: each thread converts 32 floats
    {
        int r = t >> 2;
        int k0 = (t & 3) * 32;
        const float* ar = A + (size_t)(r0 + r) * 128 + k0;
#pragma unroll
        for (int j = 0; j < 4; j++) {
            float4 f0 = *(const float4*)(ar + 8 * j);
            float4 f1 = *(const float4*)(ar + 8 * j + 4);
            float x[8] = {f0.x, f0.y, f0.z, f0.w, f1.x, f1.y, f1.z, f1.w};
            bf16x8 vh, vl;
#pragma unroll
            for (int q = 0; q < 8; q++) {
                short hh = f2bf(x[q]);
                vh[q] = hh;
                vl[q] = f2bf(x[q] - bf2f(hh));
            }
            *(bf16x8*)(sAh + r * 136 + k0 + 8 * j) = vh;
            *(bf16x8*)(sAl + r * 136 + k0 + 8 * j) = vl;
        }
    }
    __syncthreads();
    int lane = t & 63, wv = t >> 6;
    int lm = lane & 15, quad = lane >> 4;
    int m0 = wv * 16;
    bf16x8 aH[4], aL[4];
#pragma unroll
    for (int kt = 0; kt < 4; kt++) {
        aH[kt] = *(const bf16x8*)(sAh + (m0 + lm) * 136 + kt * 32 + quad * 8);
        aL[kt] = *(const bf16x8*)(sAl + (m0 + lm) * 136 + kt * 32 + quad * 8);
    }
#pragma unroll
    for (int nt = 0; nt < 8; nt++) {
        const short* blp = BT_lo + (nt * 16 + lm) * 128 + quad * 8;
        floatx4 acc = (floatx4){0.f, 0.f, 0.f, 0.f};
#pragma unroll
        for (int kt = 0; kt < 4; kt++) {
            bf16x8 bH = *(const bf16x8*)(sBh + (nt * 16 + lm) * 136 + kt * 32 + quad * 8);
            bf16x8 bL = *(const bf16x8*)(blp + kt * 32);
            acc = __builtin_amdgcn_mfma_f32_16x16x32_bf16(aH[kt], bH, acc, 0, 0, 0);
            acc = __builtin_amdgcn_mfma_f32_16x16x32_bf16(aL[kt], bH, acc, 0, 0, 0);
            acc = __builtin_amdgcn_mfma_f32_16x16x32_bf16(aH[kt], bL, acc, 0, 0, 0);
        }
        int col = nt * 16 + lm;
        if (col < ncols) {
            float bv = bias ? bias[col] : 0.f;
#pragma unroll
            for (int r = 0; r < 4; r++) {
                int row = r0 + m0 + quad * 4 + r;
                C[(size_t)row * ncols + col] = acc[r] + bv;
            }
        }
    }
}

// ---------------- MFMA GEMM: [N,128](fp32) @ WbT(bf16 [n][k]) -> bf16 out ----------------
// 64 rows/block, full N=128. A converted fp32->bf16 into LDS (+8 pad = 2-way bank, free).
// Optional fused el/er epilogue: one extra 16-col MFMA tile from WelT (global, L2-hot)
// reusing the same A fragments — replaces the separate k_elr pass over 10MB feat.
__global__ __launch_bounds__(256) void k_gemm_mfma(const float* __restrict__ A,
                                                   const short* __restrict__ WbT,
                                                   const float* __restrict__ bias,
                                                   short* __restrict__ C,
                                                   const short* __restrict__ WelT,
                                                   float* __restrict__ el,
                                                   float* __restrict__ er,
                                                   int H) {
    __shared__ short sA[64 * 136];
    __shared__ short sB[128 * 136];
    int t = threadIdx.x;
    int r0 = blockIdx.x * 64;
    // stage B: each thread copies 64 bf16
    {
        int n = t >> 1;
        int k0 = (t & 1) * 64;
#pragma unroll
        for (int j = 0; j < 8; j++) {
            bf16x8 v = *(const bf16x8*)(WbT + n * 128 + k0 + 8 * j);
            *(bf16x8*)(sB + n * 136 + k0 + 8 * j) = v;
        }
    }
    // stage A: each thread converts 32 floats
    {
        int r = t >> 2;
        int k0 = (t & 3) * 32;
        const float* ar = A + (size_t)(r0 + r) * 128 + k0;
#pragma unroll
        for (int j = 0; j < 4; j++) {
            float4 f0 = *(const float4*)(ar + 8 * j);
            float4 f1 = *(const float4*)(ar + 8 * j + 4);
            bf16x8 v;
            v[0] = f2bf(f0.x); v[1] = f2bf(f0.y); v[2] = f2bf(f0.z); v[3] = f2bf(f0.w);
            v[4] = f2bf(f1.x); v[5] = f2bf(f1.y); v[6] = f2bf(f1.z); v[7] = f2bf(f1.w);
            *(bf16x8*)(sA + r * 136 + k0 + 8 * j) = v;
        }
    }
    __syncthreads();
    int lane = t & 63, wv = t >> 6;
    int lm = lane & 15, quad = lane >> 4;
    int m0 = wv * 16;
    bf16x8 aF[4];
#pragma unroll
    for (int kt = 0; kt < 4; kt++)
        aF[kt] = *(const bf16x8*)(sA + (m0 + lm) * 136 + kt * 32 + quad * 8);
#pragma unroll
    for (int nt = 0; nt < 8; nt++) {
        floatx4 acc = (floatx4){0.f, 0.f, 0.f, 0.f};
#pragma unroll
        for (int kt = 0; kt < 4; kt++) {
            bf16x8 bF = *(const bf16x8*)(sB + (nt * 16 + lm) * 136 + kt * 32 + quad * 8);
            acc = __builtin_amdgcn_mfma_f32_16x16x32_bf16(aF[kt], bF, acc, 0, 0, 0);
        }
        int col = nt * 16 + lm;
        float bv = bias ? bias[col] : 0.f;
#pragma unroll
        for (int r = 0; r < 4; r++) {
            int row = r0 + m0 + quad * 4 + r;
            C[(size_t)row * 128 + col] = f2bf(acc[r] + bv);
        }
    }
    // fused el/er tile: cols 0..7 = el heads, 8..15 = er heads (H=1: col0=el, col1=er)
    if (WelT) {
        floatx4 acc = (floatx4){0.f, 0.f, 0.f, 0.f};
#pragma unroll
        for (int kt = 0; kt < 4; kt++) {
            bf16x8 wF = *(const bf16x8*)(WelT + lm * 128 + kt * 32 + quad * 8);
            acc = __builtin_amdgcn_mfma_f32_16x16x32_bf16(aF[kt], wF, acc, 0, 0, 0);
        }
        if (H == 8) {
#pragma unroll
            for (int r = 0; r < 4; r++) {
                int row = r0 + m0 + quad * 4 + r;
                if (lm < 8) el[(size_t)row * 8 + lm] = acc[r];
                else        er[(size_t)row * 8 + (lm - 8)] = acc[r];
            }
        } else {
#pragma unroll
            for (int r = 0; r < 4; r++) {
                int row = r0 + m0 + quad * 4 + r;
                if (lm == 0) el[row] = acc[r];
                if (lm == 1) er[row] = acc[r];
            }
        }
    }
}

// ---------------- softmax over 100 logits, wave per node, barrier-free ----------------
__global__ __launch_bounds__(256) void k_smax100(const float* __restrict__ logits,
                                                 float* __restrict__ s) {
    int lane = threadIdx.x & 63;
    int n = blockIdx.x * 4 + (threadIdx.x >> 6);
    if (n >= N_) return;
    bool act = lane < 50;
    float2 v = make_float2(-INFINITY, -INFINITY);
    if (act) v = *(const float2*)(logits + (size_t)n * 100 + 2 * lane);
    float mx = fmaxf(v.x, v.y);
#pragma unroll
    for (int off = 1; off < 64; off <<= 1) mx = fmaxf(mx, __shfl_xor(mx, off));
    float e0 = act ? __expf(v.x - mx) : 0.f;
    float e1 = act ? __expf(v.y - mx) : 0.f;
    float sm = e0 + e1;
#pragma unroll
    for (int off = 1; off < 64; off <<= 1) sm += __shfl_xor(sm, off);
    float inv = 1.f / sm;
    if (act) *(float2*)(s + (size_t)n * 100 + 2 * lane) = make_float2(e0 * inv, e1 * inv);
}

// ---------------- GAT edge-softmax + aggregate (wave per dst node, bf16 feat) ----------------
// v4 (proven 824us config). Do not re-fuse stats (atomic-burst, r7) and do not
// rewrite pass 1 (compiler pipelining, r7).
template <int H>
__global__ __launch_bounds__(256) void k_gat_agg(const short* __restrict__ feat,
                                                 const float* __restrict__ el,
                                                 const float* __restrict__ er,
                                                 const int* __restrict__ rowptr,
                                                 const int* __restrict__ srcv,
                                                 const float* __restrict__ bias,
                                                 float* __restrict__ xout) {
    int lane = threadIdx.x & 63;
    int gw = (blockIdx.x * blockDim.x + threadIdx.x) >> 6;
    int nw = (gridDim.x * blockDim.x) >> 6;
    constexpr int LH = (H == 8) ? 3 : 0;
    int h = lane & (H - 1);
    int f0 = 2 * lane;
    int hf = (H == 8) ? (lane >> 3) : 0;   // head owning this lane's feature slice

    for (int n = gw; n < N_; n += nw) {
        int beg = rowptr[n], end = rowptr[n + 1];
        if (beg == end) {
            *(float2*)(xout + (size_t)n * 128 + f0) = *(const float2*)(bias + f0);
            continue;
        }
        float ern = er[(size_t)n * H + h];
        // ---- pass 1: online softmax stats ----
        float m = -INFINITY, ss = 0.f;
        for (int e = beg + (lane >> LH); e < end; e += (64 >> LH)) {
            int sI = srcv[e];
            float x = el[(size_t)sI * H + h] + ern;
            float lr = x > 0.f ? x : 0.2f * x;
            if (lr > m) { ss = ss * __expf(m - lr) + 1.f; m = lr; }
            else ss += __expf(lr - m);
        }
#pragma unroll
        for (int off = H; off < 64; off <<= 1) {
            float om = __shfl_xor(m, off);
            float os = __shfl_xor(ss, off);
            float nm = fmaxf(m, om);
            float p1 = (m == -INFINITY) ? 0.f : ss * __expf(m - nm);
            float p2 = (om == -INFINITY) ? 0.f : os * __expf(om - nm);
            m = nm; ss = p1 + p2;
        }
        // after butterfly each lane holds (m, ss) for its own head h = lane&(H-1)
        float inv_d = 1.f / ss;
        // ---- pass 2: 2x interleaved chunked aggregation ----
        int endm1 = end - 1;
        float accx = 0.f, accy = 0.f;
        for (int e0 = beg; e0 < end; e0 += 16) {
            int le = lane >> 3;
            int eLA = e0 + le, eLB = e0 + 8 + le;
            int eCA = eLA <= endm1 ? eLA : endm1;
            int eCB = eLB <= endm1 ? eLB : endm1;
            int sLA = srcv[eCA];
            int sLB = srcv[eCB];
            float xA = el[(size_t)sLA * H + h] + ern;
            float xB = el[(size_t)sLB * H + h] + ern;
            float lrA = xA > 0.f ? xA : 0.2f * xA;
            float lrB = xB > 0.f ? xB : 0.2f * xB;
            float wA = __expf(lrA - m) * inv_d;
            float wB = __expf(lrB - m) * inv_d;
            if (eLA > endm1) wA = 0.f;
            if (eLB > endm1) wB = 0.f;
            bool haveB = (e0 + 8) < end;    // wave-uniform
            unsigned int uuA[8], uuB[8];
#pragma unroll
            for (int j = 0; j < 8; j++) {
                int sj = __builtin_amdgcn_readlane(sLA, j * 8);
                uuA[j] = *(const unsigned int*)(feat + (size_t)sj * 128 + f0);
            }
            if (haveB) {
#pragma unroll
                for (int j = 0; j < 8; j++) {
                    int sj = __builtin_amdgcn_readlane(sLB, j * 8);
                    uuB[j] = *(const unsigned int*)(feat + (size_t)sj * 128 + f0);
                }
            }
#pragma unroll
            for (int j = 0; j < 8; j++) {
                float aj;
                if (H == 8) aj = __shfl(wA, j * 8 + hf);
                else        aj = rdlane(wA, j * 8);
                accx += aj * bflo(uuA[j]);
                accy += aj * bfhi(uuA[j]);
            }
            if (haveB) {
#pragma unroll
                for (int j = 0; j < 8; j++) {
                    float aj;
                    if (H == 8) aj = __shfl(wB, j * 8 + hf);
                    else        aj = rdlane(wB, j * 8);
                    accx += aj * bflo(uuB[j]);
                    accy += aj * bfhi(uuB[j]);
                }
            }
        }
        float2 b2 = *(const float2*)(bias + f0);
        *(float2*)(xout + (size_t)n * 128 + f0) = make_float2(accx + b2.x, accy + b2.y);
    }
}

// ---------------- BN stats ----------------
__global__ __launch_bounds__(256) void k_bn_stats(const float* __restrict__ x,
                                                  float* __restrict__ sum,
                                                  float* __restrict__ sumsq) {
    __shared__ float ls[256], lq[256];
    int t = threadIdx.x;
    int col = t & 127, half = t >> 7;
    float s = 0.f, q = 0.f;
    for (int r = blockIdx.x * 2 + half; r < N_; r += gridDim.x * 2) {
        float v = x[(size_t)r * 128 + col];
        s += v; q += v * v;
    }
    ls[t] = s; lq[t] = q;
    __syncthreads();
    if (t < 128) {
        atomicAdd(&sum[col], ls[t] + ls[t + 128]);
        atomicAdd(&sumsq[col], lq[t] + lq[t + 128]);
    }
}

// ---------------- BN apply + ELU + residual (+mask) ----------------
__global__ __launch_bounds__(256) void k_bn_apply(const float* __restrict__ x,
                                                  const float* __restrict__ hprev,
                                                  const float* __restrict__ sum,
                                                  const float* __restrict__ sumsq,
                                                  const float* __restrict__ g,
                                                  const float* __restrict__ b,
                                                  float* __restrict__ out, int do_mask) {
    int i = blockIdx.x * blockDim.x + threadIdx.x;
    if (i >= N_ * 128) return;
    int c = i & 127;
    const float invN = 1.f / (float)N_;
    float mu = sum[c] * invN;
    float var = sumsq[c] * invN - mu * mu;
    float inv = rsqrtf(var + 1e-5f);
    float y = g[c] * (x[i] - mu) * inv + b[c];
    y = y > 0.f ? y : (__expf(y) - 1.f);
    float hv = hprev[i] + y;
    if (do_mask && isinf(hv)) hv = 1e9f;
    out[i] = hv;
}

// ---------------- h_coarse partials ----------------
__global__ __launch_bounds__(512) void k_coarse_part(const float* __restrict__ s,
                                                     const float* __restrict__ hf,
                                                     float* __restrict__ part) {
    int t = threadIdx.x;
    int c = t & 127;
    int g = t >> 7;        // 0..3
    int lane = t & 63;
    float acc[25];
#pragma unroll
    for (int a = 0; a < 25; a++) acc[a] = 0.f;
    int n0 = blockIdx.x * CR_;
    for (int n = n0; n < n0 + CR_; n += 2) {
        float hv0 = hf[(size_t)n * 128 + c];
        float hv1 = hf[(size_t)(n + 1) * 128 + c];
        float sv0 = 0.f, sv1 = 0.f;
        if (lane < 25) {
            sv0 = s[(size_t)n * 100 + 25 * g + lane];
            sv1 = s[(size_t)(n + 1) * 100 + 25 * g + lane];
        }
#pragma unroll
        for (int a = 0; a < 25; ++a) {
            float a0 = rdlane(sv0, a);
            float a1 = rdlane(sv1, a);
            acc[a] += a0 * hv0 + a1 * hv1;
        }
    }
    float* dstp = part + (size_t)blockIdx.x * 12800 + (size_t)(25 * g) * 128 + c;
#pragma unroll
    for (int a = 0; a < 25; a++) dstp[a * 128] = acc[a];
}

// ---------------- reduce partials -> hc[100][128] ----------------
__global__ __launch_bounds__(256) void k_coarse_reduce(const float* __restrict__ part,
                                                       float* __restrict__ hc) {
    int i = blockIdx.x * blockDim.x + threadIdx.x;  // 12800 total
    if (i >= 12800) return;
    float s0 = 0.f, s1 = 0.f, s2 = 0.f, s3 = 0.f;
    for (int b = 0; b < CB_; b += 4) {
        s0 += part[(size_t)(b + 0) * 12800 + i];
        s1 += part[(size_t)(b + 1) * 12800 + i];
        s2 += part[(size_t)(b + 2) * 12800 + i];
        s3 += part[(size_t)(b + 3) * 12800 + i];
    }
    hc[i] = (s0 + s1) + (s2 + s3);
}

// ---------------- h = mask(0.5*h_fine + 0.5*(s@h_coarse)) ----------------
__global__ __launch_bounds__(256) void k_combine(const float* __restrict__ s,
                                                 const float* __restrict__ hc,
                                                 const float* __restrict__ hfine,
                                                 float* __restrict__ hout) {
    __shared__ float ssh[16 * 100];
    int t = threadIdx.x;
    int n0 = blockIdx.x * 16;
    for (int u = t; u < 1600; u += 256) ssh[u] = s[(size_t)n0 * 100 + u];
    __syncthreads();
    int c = t & 127, g = t >> 7;
    float acc[8];
#pragma unroll
    for (int r = 0; r < 8; r++) acc[r] = 0.f;
    const float* hcp = hc + c;
    for (int a = 0; a < 100; a += 4) {
        float h0 = hcp[(a + 0) * 128];
        float h1 = hcp[(a + 1) * 128];
        float h2 = hcp[(a + 2) * 128];
        float h3 = hcp[(a + 3) * 128];
#pragma unroll
        for (int r = 0; r < 8; r++) {
            float4 sv = *(const float4*)(ssh + (g * 8 + r) * 100 + a);
            acc[r] += sv.x * h0 + sv.y * h1 + sv.z * h2 + sv.w * h3;
        }
    }
#pragma unroll
    for (int r = 0; r < 8; r++) {
        int row = n0 + g * 8 + r;
        float v = 0.5f * hfine[(size_t)row * 128 + c] + 0.5f * acc[r];
        if (isinf(v)) v = 1e9f;
        hout[(size_t)row * 128 + c] = v;
    }
}

// ---------------- prep: Wm2 [128][64] fp32 -> Wm2T bf16 [64][128] ----------------
__global__ __launch_bounds__(256) void k_prep_w(const float* __restrict__ Wm2,
                                                short* __restrict__ Wm2T) {
    int i = blockIdx.x * blockDim.x + threadIdx.x;  // 8192 total
    if (i >= 64 * 128) return;
    int n = i & 63, k = i >> 6;
    Wm2T[n * 128 + k] = f2bf(Wm2[k * 64 + n]);
}

// ---------------- edge MLP readout: dst-sorted order, barrier-free persistent MFMA ----------------
// v2 — LOCAL OPTIMUM at ~53.5us, VGPR 84. Do not register-diet (v3: spills, 3x dur).
// Do not 2-tile (v4: compiler serializes the B-tile loads, occupancy drops, +6us).
__global__ __launch_bounds__(256) void k_edge_mlp3(const short* __restrict__ Pb,
                                                   const short* __restrict__ Qb,
                                                   const int* __restrict__ srcv,
                                                   const unsigned short* __restrict__ dstv,
                                                   const int* __restrict__ eidv,
                                                   const short* __restrict__ Wm2T,
                                                   const float* __restrict__ bm2,
                                                   const float* __restrict__ Wm3,
                                                   const float* __restrict__ bm3,
                                                   float* __restrict__ zout) {
    __shared__ short sW[64 * 128];  // 16 KiB
    int t = threadIdx.x;
    // stage Wm2T -> LDS with 16B-unit XOR swizzle: phys_unit = n*16 + (k16 ^ (n&15))
    for (int u = t; u < 1024; u += 256) {
        int n = u >> 4, k16 = u & 15;
        int phys = (n << 4) | (k16 ^ (n & 15));
        *(bf16x8*)(sW + phys * 8) = *(const bf16x8*)(Wm2T + n * 128 + k16 * 8);
    }
    int lane = t & 63;
    int lm = lane & 15, quad = lane >> 4;
    float bv[4], w30[4], w31[4];
#pragma unroll
    for (int nt = 0; nt < 4; nt++) {
        int n = nt * 16 + lm;
        bv[nt] = bm2[n]; w30[nt] = Wm3[2 * n]; w31[nt] = Wm3[2 * n + 1];
    }
    float b30 = bm3[0], b31 = bm3[1];
    __syncthreads();

    int gw = (blockIdx.x * blockDim.x + t) >> 6;
    int nw = (gridDim.x * blockDim.x) >> 6;

    for (int tile = gw; tile < E_ / 16; tile += nw) {
        int p0 = tile * 16;
        int sI = srcv[p0 + lm];
        int dI = (int)dstv[p0 + lm];
        const short* pr = Pb + (size_t)sI * 128 + quad * 8;
        const short* qr = Qb + (size_t)dI * 128 + quad * 8;
        // issue all 8 gathers up-front (latency hidden within wave)
        uint4 pu[4], qu[4];
#pragma unroll
        for (int kt = 0; kt < 4; kt++) {
            pu[kt] = *(const uint4*)(pr + kt * 32);
            qu[kt] = *(const uint4*)(qr + kt * 32);
        }
        bf16x8 aF[4];
#pragma unroll
        for (int kt = 0; kt < 4; kt++) {
            unsigned int pv[4] = {pu[kt].x, pu[kt].y, pu[kt].z, pu[kt].w};
            unsigned int qv[4] = {qu[kt].x, qu[kt].y, qu[kt].z, qu[kt].w};
            union { uint4 u; bf16x8 v; } cv;
            unsigned int rr[4];
#pragma unroll
            for (int j = 0; j < 4; j++) {
                float fl = fmaxf(bflo(pv[j]) + bflo(qv[j]), 0.f);
                float fh = fmaxf(bfhi(pv[j]) + bfhi(qv[j]), 0.f);
                rr[j] = (unsigned int)(unsigned short)f2bf(fl) |
                        ((unsigned int)(unsigned short)f2bf(fh) << 16);
            }
            cv.u.x = rr[0]; cv.u.y = rr[1]; cv.u.z = rr[2]; cv.u.w = rr[3];
            aF[kt] = cv.v;
        }
        float pz0[4] = {0.f, 0.f, 0.f, 0.f};
        float pz1[4] = {0.f, 0.f, 0.f, 0.f};
#pragma unroll
        for (int nt = 0; nt < 4; nt++) {
            floatx4 acc = (floatx4){0.f, 0.f, 0.f, 0.f};
#pragma unroll
            for (int kt = 0; kt < 4; kt++) {
                int phys = ((nt * 16 + lm) << 4) | (((kt << 2) | quad) ^ lm);
                bf16x8 bF = *(const bf16x8*)(sW + phys * 8);
                acc = __builtin_amdgcn_mfma_f32_16x16x32_bf16(aF[kt], bF, acc, 0, 0, 0);
            }
#pragma unroll
            for (int r = 0; r < 4; r++) {
                float u = fmaxf(acc[r] + bv[nt], 0.f);
                pz0[r] += u * w30[nt];
                pz1[r] += u * w31[nt];
            }
        }
#pragma unroll
        for (int off = 1; off < 16; off <<= 1) {
#pragma unroll
            for (int r = 0; r < 4; r++) {
                pz0[r] += __shfl_xor(pz0[r], off);
                pz1[r] += __shfl_xor(pz1[r], off);
            }
        }
        if (lm < 4) {
            int eid = eidv[p0 + quad * 4 + lm];
            float z0 = pz0[lm] + b30;
            float z1 = pz1[lm] + b31;
            if (isinf(z0)) z0 = 1e9f;
            if (isinf(z1)) z1 = 1e9f;
            *(float2*)(zout + (size_t)eid * 2) = make_float2(z0, z1);
        }
    }
}

extern "C" void kernel_launch(void* const* d_in, const int* in_sizes, int n_in,
                              void* d_out, int out_size, void* d_ws, size_t ws_size,
                              hipStream_t stream) {
    const float* h_in  = (const float*)d_in[0];
    const int*   src   = (const int*)d_in[2];
    const int*   dst   = (const int*)d_in[3];
    const float* W_emb = (const float*)d_in[4];
    const float* b_emb = (const float*)d_in[5];
    const float* Wg    = (const float*)d_in[6];
    const float* alg   = (const float*)d_in[7];
    const float* arg_  = (const float*)d_in[8];
    const float* bg    = (const float*)d_in[9];
    const float* gam   = (const float*)d_in[10];
    const float* bet   = (const float*)d_in[11];
    const float* W3    = (const float*)d_in[12];
    const float* al3   = (const float*)d_in[13];
    const float* ar3   = (const float*)d_in[14];
    const float* b3    = (const float*)d_in[15];
    const float* gam3  = (const float*)d_in[16];
    const float* bet3  = (const float*)d_in[17];
    const float* Wa    = (const float*)d_in[18];
    const float* ba    = (const float*)d_in[19];
    const float* Wm1   = (const float*)d_in[20];
    const float* bm1   = (const float*)d_in[21];
    const float* Wm2   = (const float*)d_in[22];
    const float* bm2   = (const float*)d_in[23];
    const float* Wm3   = (const float*)d_in[24];
    const float* bm3   = (const float*)d_in[25];

    float* zout = (float*)d_out;
    float* sout = zout + (size_t)E_ * 2;

    float* ws = (float*)d_ws;
    size_t o = 0;
    float* h_cur = ws + o; o += (size_t)N_ * 128;
    float* xbuf  = ws + o; o += (size_t)N_ * 128;
    float* featb = ws + o; o += (size_t)N_ * 128;   // reused: bf16 feat, coarse partials, bf16 P/Q
    float* el    = ws + o; o += (size_t)N_ * 8;
    float* er    = ws + o; o += (size_t)N_ * 8;
    float* colsum = ws + o; o += 128;
    float* colsq  = ws + o; o += 128;
    float* hc     = ws + o; o += 100 * 128;
    short* Wm2T = (short*)(ws + o); o += (64 * 128) / 2;
    short* WbT6 = (short*)(ws + o); o += (6 * 16384) / 2;
    short* WelT = (short*)(ws + o); o += (4 * 2048) / 2;
    short* WembT_hi = (short*)(ws + o); o += 16384 / 2;
    short* WembT_lo = (short*)(ws + o); o += 16384 / 2;
    short* WaT_hi   = (short*)(ws + o); o += 16384 / 2;
    short* WaT_lo   = (short*)(ws + o); o += 16384 / 2;
    int* counts = (int*)(ws + o); o += N_;
    int* rowptr = (int*)(ws + o); o += N_ + 4;
    int* cursor = (int*)(ws + o); o += N_;
    int* srcv   = (int*)(ws + o); o += E_;
    unsigned short* dstv = (unsigned short*)(ws + o); o += E_ / 2;
    int* eidv   = (int*)(ws + o); o += E_;
    int* bsum   = (int*)(ws + o); o += SNB_ + 4;

    short* featw = (short*)featb;  // bf16 per-layer projection

    // ---- CSR build (parallel scan; excl scratch reuses eidv pre-fill) ----
    hipMemsetAsync(counts, 0, N_ * sizeof(int), stream);
    k_count<<<1024, 256, 0, stream>>>(dst, counts);
    k_scanA<<<SNB_, 256, 0, stream>>>(counts, eidv, bsum);
    k_scanB<<<1, 256, 0, stream>>>(bsum);
    k_scanC<<<SNB_ + 1, 256, 0, stream>>>(eidv, bsum, rowptr, cursor);
    k_fill<<<1024, 256, 0, stream>>>(src, dst, cursor, srcv, dstv, eidv);
    k_prep_w<<<32, 256, 0, stream>>>(Wm2, Wm2T);
    k_prep_all<<<384, 256, 0, stream>>>(Wg, W3, Wm1, WbT6);
    k_prep_wela<<<32, 256, 0, stream>>>(Wg, alg, arg_, W3, al3, ar3, WelT);
    k_prep_hilo<<<128, 256, 0, stream>>>(W_emb, Wa, WembT_hi, WembT_lo, WaT_hi, WaT_lo);

    // ---- embedding (fp32-accurate via hi/lo MFMA) ----
    k_mfma_hilo<<<N_ / 64, 256, 0, stream>>>(h_in, WembT_hi, WembT_lo, b_emb, h_cur, 128);

    // ---- layer 0 (H=8) ----
    k_gemm_mfma<<<N_ / 64, 256, 0, stream>>>(h_cur, WbT6 + 0 * 16384, nullptr, featw,
                                             WelT + 0 * 2048, el, er, 8);
    k_gat_agg<8><<<2048, 256, 0, stream>>>(featw, el, er, rowptr, srcv, bg + 0 * 128, xbuf);
    hipMemsetAsync(colsum, 0, 256 * sizeof(float), stream);
    k_bn_stats<<<512, 256, 0, stream>>>(xbuf, colsum, colsq);
    k_bn_apply<<<(N_ * 128) / 256, 256, 0, stream>>>(xbuf, h_cur, colsum, colsq,
                                                     gam + 0 * 128, bet + 0 * 128, h_cur, 1);

    // ---- layer 1 (biGAT, H=8) ----
    k_mfma_hilo<<<N_ / 64, 256, 0, stream>>>(h_cur, WaT_hi, WaT_lo, ba, xbuf, 100);
    k_smax100<<<N_ / 4, 256, 0, stream>>>(xbuf, sout);
    k_gemm_mfma<<<N_ / 64, 256, 0, stream>>>(h_cur, WbT6 + 1 * 16384, nullptr, featw,
                                             WelT + 1 * 2048, el, er, 8);
    k_gat_agg<8><<<2048, 256, 0, stream>>>(featw, el, er, rowptr, srcv, bg + 1 * 128, xbuf);
    hipMemsetAsync(colsum, 0, 256 * sizeof(float), stream);
    k_bn_stats<<<512, 256, 0, stream>>>(xbuf, colsum, colsq);
    k_bn_apply<<<(N_ * 128) / 256, 256, 0, stream>>>(xbuf, h_cur, colsum, colsq,
                                                     gam + 1 * 128, bet + 1 * 128, xbuf, 0);
    k_coarse_part<<<CB_, 512, 0, stream>>>(sout, xbuf, featb);
    k_coarse_reduce<<<50, 256, 0, stream>>>(featb, hc);
    k_combine<<<N_ / 16, 256, 0, stream>>>(sout, hc, xbuf, h_cur);

    // ---- layer 2 (H=8) ----
    k_gemm_mfma<<<N_ / 64, 256, 0, stream>>>(h_cur, WbT6 + 2 * 16384, nullptr, featw,
                                             WelT + 2 * 2048, el, er, 8);
    k_gat_agg<8><<<2048, 256, 0, stream>>>(featw, el, er, rowptr, srcv, bg + 2 * 128, xbuf);
    hipMemsetAsync(colsum, 0, 256 * sizeof(float), stream);
    k_bn_stats<<<512, 256, 0, stream>>>(xbuf, colsum, colsq);
    k_bn_apply<<<(N_ * 128) / 256, 256, 0, stream>>>(xbuf, h_cur, colsum, colsq,
                                                     gam + 2 * 128, bet + 2 * 128, h_cur, 1);

    // ---- layer 3 (H=1) ----
    k_gemm_mfma<<<N_ / 64, 256, 0, stream>>>(h_cur, WbT6 + 3 * 16384, nullptr, featw,
                                             WelT + 3 * 2048, el, er, 1);
    k_gat_agg<1><<<2048, 256, 0, stream>>>(featw, el, er, rowptr, srcv, b3, xbuf);
    hipMemsetAsync(colsum, 0, 256 * sizeof(float), stream);
    k_bn_stats<<<512, 256, 0, stream>>>(xbuf, colsum, colsq);
    k_bn_apply<<<(N_ * 128) / 256, 256, 0, stream>>>(xbuf, h_cur, colsum, colsq,
                                                     gam3, bet3, h_cur, 1);

    // ---- edge MLP readout: Pb = bf16(h@Wm1[:128]+bm1), Qb = bf16(h@Wm1[128:]) ----
    short* Pb = (short*)featb;
    short* Qb = Pb + (size_t)N_ * 128;
    k_gemm_mfma<<<N_ / 64, 256, 0, stream>>>(h_cur, WbT6 + 4 * 16384, bm1, Pb,
                                             nullptr, nullptr, nullptr, 0);
    k_gemm_mfma<<<N_ / 64, 256, 0, stream>>>(h_cur, WbT6 + 5 * 16384, nullptr, Qb,
                                             nullptr, nullptr, nullptr, 0);
    k_edge_mlp3<<<2048, 256, 0, stream>>>(Pb, Qb, srcv, dstv, eidv, Wm2T, bm2, Wm3, bm3, zout);
}